// Round 8
// baseline (560.564 us; speedup 1.0000x reference)
//
#include <hip/hip_runtime.h>
#include <math.h>

#define NXR 8192
#define NCR 8192
#define HD  512

typedef short s16x8 __attribute__((ext_vector_type(8)));
typedef float f32x4 __attribute__((ext_vector_type(4)));
typedef unsigned short u16;

struct P11 { const float* p[11]; };
struct P3  { const float* p[3]; };

__device__ inline u16 f2bf(float f) {
    unsigned int u = __float_as_uint(f);
    u = (u + 0x7FFFu + ((u >> 16) & 1u)) >> 16;
    return (u16)u;
}
__device__ inline float bf2f(u16 h) {
    return __uint_as_float(((unsigned int)h) << 16);
}

// ---------------------------------------------------------------------------
// Fused weight transpose + bf16 convert: out[z][n][k] = (bf16)in_z[k][n].
// Layout: z = l*3+net for hidden layers, 9 = QWo, 10 = KWo. grid (16,16,11).
// ---------------------------------------------------------------------------
__global__ __launch_bounds__(256) void transpose_w_all(
    P11 srcs, u16* __restrict__ out)
{
    const float* in = srcs.p[blockIdx.z];
    u16* o = out + (size_t)blockIdx.z * HD * HD;
    __shared__ float tile[32][33];
    int bx = blockIdx.x * 32, by = blockIdx.y * 32;
    int tx = threadIdx.x & 31, ty = threadIdx.x >> 5;
    for (int r = ty; r < 32; r += 8)
        tile[r][tx] = in[(size_t)(by + r) * HD + bx + tx];
    __syncthreads();
    for (int r = ty; r < 32; r += 8)
        o[(size_t)(bx + r) * HD + by + tx] = f2bf(tile[tx][r]);
}

// ---------------------------------------------------------------------------
// Layer 0: H[z][row][n] = bf16(sin(sum_{k<3} X[row][k]*W0[k][n] + b0[n]))
// net = net_base + z selects x (net 0) vs c (nets 1,2). grid (16384,1,nz).
// ---------------------------------------------------------------------------
__global__ __launch_bounds__(256) void layer0_all(
    const float* __restrict__ x, const float* __restrict__ c,
    P3 W0p, P3 b0p, u16* __restrict__ H, int net_base)
{
    int z = blockIdx.z;
    int net = net_base + z;
    const float* X  = (net == 0) ? x : c;
    const float* W0 = W0p.p[z];
    const float* b0 = b0p.p[z];
    u16* Hn = H + (size_t)z * NXR * HD;

    int idx = blockIdx.x * 256 + threadIdx.x;
    int n = idx & (HD - 1);
    int row = idx >> 9;
    float v = X[row * 3 + 0] * W0[n] + X[row * 3 + 1] * W0[HD + n] +
              X[row * 3 + 2] * W0[2 * HD + n] + b0[n];
    Hn[idx] = f2bf(__sinf(v));
}

// ---------------------------------------------------------------------------
// Multi-net bf16 MFMA GEMM, LDS-FREE: fragments loaded straight from global
// into VGPRs (A rows and Bt rows are 16B-contiguous per lane). No barriers;
// full K unroll lets the compiler keep loads several iters in flight.
// ---------------------------------------------------------------------------
template<int ACT>
__global__ __launch_bounds__(256) void gemm_bt_multi(
    const u16* __restrict__ Abase, const u16* __restrict__ Wt0, size_t wstride,
    P3 bias, u16* __restrict__ Cbase)
{
    const int net = blockIdx.z;
    const u16* A  = Abase + (size_t)net * NXR * HD;
    const u16* Bt = Wt0 + (size_t)net * wstride;
    const float* bias_p = bias.p[net];
    u16* C = Cbase + (size_t)net * NXR * HD;

    const int tid  = threadIdx.x;
    const int wave = tid >> 6;
    const int lane = tid & 63;
    const int wr = wave >> 1, wc = wave & 1;
    const int row0 = blockIdx.x * 128;
    const int col0 = blockIdx.y * 128;

    const int qm = lane & 15;
    const int qk = (lane >> 4) * 8;

    const u16* ap = A  + (size_t)(row0 + wr * 64 + qm) * HD + qk;
    const u16* bp = Bt + (size_t)(col0 + wc * 64 + qm) * HD + qk;

    f32x4 acc[4][4] = {};

#pragma unroll
    for (int kt = 0; kt < HD; kt += 32) {
        s16x8 af[4], bfr[4];
#pragma unroll
        for (int t = 0; t < 4; ++t) {
            af[t]  = *(const s16x8*)(ap + (size_t)t * 16 * HD + kt);
            bfr[t] = *(const s16x8*)(bp + (size_t)t * 16 * HD + kt);
        }
#pragma unroll
        for (int i = 0; i < 4; ++i)
#pragma unroll
            for (int j = 0; j < 4; ++j)
                acc[i][j] = __builtin_amdgcn_mfma_f32_16x16x32_bf16(af[i], bfr[j], acc[i][j], 0, 0, 0);
    }

    const int cn = lane & 15;
    const int rq = lane >> 4;
#pragma unroll
    for (int i = 0; i < 4; ++i) {
#pragma unroll
        for (int j = 0; j < 4; ++j) {
            int gcol = col0 + wc * 64 + j * 16 + cn;
            float bv = bias_p[gcol];
#pragma unroll
            for (int r = 0; r < 4; ++r) {
                int grow = row0 + wr * 64 + i * 16 + rq * 4 + r;
                float v = acc[i][j][r] + bv;
                if (ACT) v = __sinf(v);
                C[(size_t)grow * HD + gcol] = f2bf(v);
            }
        }
    }
}

// ---------------------------------------------------------------------------
// V output layer (M=3), one wave per row, fp32 out.
// ---------------------------------------------------------------------------
__global__ __launch_bounds__(256) void vout_k(
    const u16* __restrict__ H, const float* __restrict__ Wo,
    const float* __restrict__ bo, float* __restrict__ V)
{
    int wave = threadIdx.x >> 6, lane = threadIdx.x & 63;
    int row = blockIdx.x * 4 + wave;
    s16x8 hv = *(const s16x8*)(H + (size_t)row * HD + lane * 8);
    float a0 = 0, a1 = 0, a2 = 0;
#pragma unroll
    for (int j = 0; j < 8; ++j) {
        float hf = bf2f(((const u16*)&hv)[j]);
        int k = lane * 8 + j;
        a0 += hf * Wo[k * 3 + 0];
        a1 += hf * Wo[k * 3 + 1];
        a2 += hf * Wo[k * 3 + 2];
    }
#pragma unroll
    for (int d = 32; d >= 1; d >>= 1) {
        a0 += __shfl_down(a0, d);
        a1 += __shfl_down(a1, d);
        a2 += __shfl_down(a2, d);
    }
    if (lane == 0) {
        V[row * 3 + 0] = a0 + bo[0];
        V[row * 3 + 1] = a1 + bo[1];
        V[row * 3 + 2] = a2 + bo[2];
    }
}

// ---------------------------------------------------------------------------
// Fused attention, LDS-FREE: out[i][c] += sum_j sigmoid(S[i][j]) * V[j][c]
// grid (NC/128/JT, NX/128): blockIdx.x = j-slice -> consecutive blocks with
// the same slice land on the same XCD (round-robin) so K stays in local L2.
// No __syncthreads anywhere: Q/K fragments are 16B/lane direct global loads;
// the fully unrolled K-loop lets the compiler pipeline loads via vmcnt(N).
// ---------------------------------------------------------------------------
#define JT 4
__global__ __launch_bounds__(256) void attn_mfma(
    const u16* __restrict__ Q, const u16* __restrict__ K,
    const float* __restrict__ V, float* __restrict__ out)
{
    const int tid = threadIdx.x;
    const int wave = tid >> 6, lane = tid & 63;
    const int wr = wave >> 1, wc = wave & 1;
    const int row0 = blockIdx.y * 128;
    const int jsl  = blockIdx.x;

    const int qm = lane & 15, qk = (lane >> 4) * 8;
    const int cn = lane & 15, rq = lane >> 4;

    const u16* qp = Q + (size_t)(row0 + wr * 64 + qm) * HD + qk;

    float po[4][4][3] = {};   // [i][r][c], accumulated across all JT j-tiles

    for (int jt = 0; jt < JT; ++jt) {
        const int col0 = (jsl * JT + jt) * 128;
        const u16* kp = K + (size_t)(col0 + wc * 64 + qm) * HD + qk;

        // Preload this j-tile's V rows (latency hidden behind the K-loop).
        float vv[4][3];
#pragma unroll
        for (int j = 0; j < 4; ++j) {
            size_t jj = (size_t)(col0 + wc * 64 + j * 16 + cn) * 3;
            vv[j][0] = V[jj + 0];
            vv[j][1] = V[jj + 1];
            vv[j][2] = V[jj + 2];
        }

        f32x4 acc[4][4] = {};

#pragma unroll
        for (int kt = 0; kt < HD; kt += 32) {
            s16x8 af[4], bfr[4];
#pragma unroll
            for (int t = 0; t < 4; ++t) {
                af[t]  = *(const s16x8*)(qp + (size_t)t * 16 * HD + kt);
                bfr[t] = *(const s16x8*)(kp + (size_t)t * 16 * HD + kt);
            }
#pragma unroll
            for (int i = 0; i < 4; ++i)
#pragma unroll
                for (int j = 0; j < 4; ++j)
                    acc[i][j] = __builtin_amdgcn_mfma_f32_16x16x32_bf16(af[i], bfr[j], acc[i][j], 0, 0, 0);
        }

        // sigmoid + PV accumulate (rcp = v_rcp_f32, 1 ulp)
#pragma unroll
        for (int j = 0; j < 4; ++j) {
            float v0 = vv[j][0], v1 = vv[j][1], v2 = vv[j][2];
#pragma unroll
            for (int i = 0; i < 4; ++i)
#pragma unroll
                for (int r = 0; r < 4; ++r) {
                    float s = __builtin_amdgcn_rcpf(1.f + __expf(-acc[i][j][r]));
                    po[i][r][0] += s * v0;
                    po[i][r][1] += s * v1;
                    po[i][r][2] += s * v2;
                }
        }
    }

#pragma unroll
    for (int i = 0; i < 4; ++i)
#pragma unroll
        for (int r = 0; r < 4; ++r)
#pragma unroll
            for (int c = 0; c < 3; ++c) {
                float v = po[i][r][c];
                v += __shfl_down(v, 8, 16);
                v += __shfl_down(v, 4, 16);
                v += __shfl_down(v, 2, 16);
                v += __shfl_down(v, 1, 16);
                if (cn == 0)
                    atomicAdd(&out[(size_t)(row0 + wr * 64 + i * 16 + rq * 4 + r) * 3 + c], v);
            }
}

// ---------------------------------------------------------------------------
// Workspace layouts:
//  FUSED (needs >=57 MB):  [0,6) wT | [6,30) hA (3 nets) | [30,54) hB | [54,..) Vf
//  FALLBACK (38.1 MB):     [0,6) wT | [6,22) R1 (2 nets) | [22,38) R2 | [38,..) Vf
// ws_size is launch-invariant, so branching on it is graph-capture-safe.
// ---------------------------------------------------------------------------
extern "C" void kernel_launch(void* const* d_in, const int* in_sizes, int n_in,
                              void* d_out, int out_size, void* d_ws, size_t ws_size,
                              hipStream_t stream)
{
    const float* x   = (const float*)d_in[0];
    const float* c   = (const float*)d_in[1];
    const float* QW0 = (const float*)d_in[2];
    const float* Qb0 = (const float*)d_in[3];
    const float* QWh = (const float*)d_in[4];
    const float* Qbh = (const float*)d_in[5];
    const float* QWo = (const float*)d_in[6];
    const float* Qbo = (const float*)d_in[7];
    const float* KW0 = (const float*)d_in[8];
    const float* Kb0 = (const float*)d_in[9];
    const float* KWh = (const float*)d_in[10];
    const float* Kbh = (const float*)d_in[11];
    const float* KWo = (const float*)d_in[12];
    const float* Kbo = (const float*)d_in[13];
    const float* VW0 = (const float*)d_in[14];
    const float* Vb0 = (const float*)d_in[15];
    const float* VWh = (const float*)d_in[16];
    const float* Vbh = (const float*)d_in[17];
    const float* VWo = (const float*)d_in[18];
    const float* Vbo = (const float*)d_in[19];

    char* ws = (char*)d_ws;
    const size_t WTN = (size_t)HD * HD;
    const size_t MB = 1048576;
    const size_t NET = (size_t)NXR * HD;

    // ---- weight transposes (1 dispatch, both paths) ----
    u16* wT = (u16*)ws;
    P11 tsrc;
    for (int l = 0; l < 3; ++l) {
        tsrc.p[l * 3 + 0] = QWh + (size_t)l * WTN;
        tsrc.p[l * 3 + 1] = KWh + (size_t)l * WTN;
        tsrc.p[l * 3 + 2] = VWh + (size_t)l * WTN;
    }
    tsrc.p[9]  = QWo;
    tsrc.p[10] = KWo;
    transpose_w_all<<<dim3(16, 16, 11), 256, 0, stream>>>(tsrc, wT);

    const int L0G = NXR * HD / 256;  // 16384
    const u16* Qb; const u16* Kb; const float* Vf;

    if (ws_size >= 57 * MB) {
        // ================= fused path =================
        u16*   hA = (u16*)(ws + 6 * MB);
        u16*   hB = (u16*)(ws + 30 * MB);
        float* Vff = (float*)(ws + 54 * MB);

        P3 w0 = {{QW0, KW0, VW0}}, b0 = {{Qb0, Kb0, Vb0}};
        layer0_all<<<dim3(L0G, 1, 3), 256, 0, stream>>>(x, c, w0, b0, hA, 0);

        dim3 g3(NXR / 128, HD / 128, 3);
        {
            P3 b = {{Qbh + 0 * HD, Kbh + 0 * HD, Vbh + 0 * HD}};
            gemm_bt_multi<1><<<g3, 256, 0, stream>>>(hA, wT + 0 * 3 * WTN, WTN, b, hB);
        }
        {
            P3 b = {{Qbh + 1 * HD, Kbh + 1 * HD, Vbh + 1 * HD}};
            gemm_bt_multi<1><<<g3, 256, 0, stream>>>(hB, wT + 1 * 3 * WTN, WTN, b, hA);
        }
        {
            P3 b = {{Qbh + 2 * HD, Kbh + 2 * HD, Vbh + 2 * HD}};
            gemm_bt_multi<1><<<g3, 256, 0, stream>>>(hA, wT + 2 * 3 * WTN, WTN, b, hB);
        }
        {
            P3 b = {{Qbo, Kbo, nullptr}};
            gemm_bt_multi<0><<<dim3(NXR / 128, HD / 128, 2), 256, 0, stream>>>(
                hB, wT + 9 * WTN, WTN, b, hA);
        }
        vout_k<<<NCR / 4, 256, 0, stream>>>(hB + 2 * NET, VWo, Vbo, Vff);

        Qb = hA; Kb = hA + NET; Vf = Vff;
    } else {
        // ================= two-phase fallback (proven 38.1 MB) =================
        u16*   R1 = (u16*)(ws + 6 * MB);
        u16*   R2 = (u16*)(ws + 22 * MB);
        float* Vff = (float*)(ws + 38 * MB);

        {
            P3 w0 = {{VW0, nullptr, nullptr}}, b0 = {{Vb0, nullptr, nullptr}};
            layer0_all<<<dim3(L0G, 1, 1), 256, 0, stream>>>(x, c, w0, b0, R1, 2);
        }
        dim3 gv(NXR / 128, HD / 128, 1);
        {
            P3 b = {{Vbh + 0 * HD, nullptr, nullptr}};
            gemm_bt_multi<1><<<gv, 256, 0, stream>>>(R1, wT + (0 * 3 + 2) * WTN, 0, b, R2);
        }
        {
            P3 b = {{Vbh + 1 * HD, nullptr, nullptr}};
            gemm_bt_multi<1><<<gv, 256, 0, stream>>>(R2, wT + (1 * 3 + 2) * WTN, 0, b, R1);
        }
        {
            P3 b = {{Vbh + 2 * HD, nullptr, nullptr}};
            gemm_bt_multi<1><<<gv, 256, 0, stream>>>(R1, wT + (2 * 3 + 2) * WTN, 0, b, R2);
        }
        vout_k<<<NCR / 4, 256, 0, stream>>>(R2, VWo, Vbo, Vff);

        {
            P3 w0 = {{QW0, KW0, nullptr}}, b0 = {{Qb0, Kb0, nullptr}};
            layer0_all<<<dim3(L0G, 1, 2), 256, 0, stream>>>(x, c, w0, b0, R1, 0);
        }
        dim3 gqk(NXR / 128, HD / 128, 2);
        {
            P3 b = {{Qbh + 0 * HD, Kbh + 0 * HD, nullptr}};
            gemm_bt_multi<1><<<gqk, 256, 0, stream>>>(R1, wT + 0 * 3 * WTN, WTN, b, R2);
        }
        {
            P3 b = {{Qbh + 1 * HD, Kbh + 1 * HD, nullptr}};
            gemm_bt_multi<1><<<gqk, 256, 0, stream>>>(R2, wT + 1 * 3 * WTN, WTN, b, R1);
        }
        {
            P3 b = {{Qbh + 2 * HD, Kbh + 2 * HD, nullptr}};
            gemm_bt_multi<1><<<gqk, 256, 0, stream>>>(R1, wT + 2 * 3 * WTN, WTN, b, R2);
        }
        {
            P3 b = {{Qbo, Kbo, nullptr}};
            gemm_bt_multi<0><<<gqk, 256, 0, stream>>>(R2, wT + 9 * WTN, WTN, b, R1);
        }
        Qb = R1; Kb = R1 + NET; Vf = Vff;
    }

    // ---- attention ----
    hipMemsetAsync(d_out, 0, (size_t)out_size * sizeof(float), stream);
    attn_mfma<<<dim3(NCR / 128 / JT, NXR / 128), 256, 0, stream>>>(
        Qb, Kb, Vf, (float*)d_out);
}

// Round 9
// 423.346 us; speedup vs baseline: 1.3241x; 1.3241x over previous
//
#include <hip/hip_runtime.h>
#include <math.h>

#define NXR 8192
#define NCR 8192
#define HD  512

typedef short s16x8 __attribute__((ext_vector_type(8)));
typedef float f32x4 __attribute__((ext_vector_type(4)));
typedef unsigned short u16;

struct P11 { const float* p[11]; };
struct P3  { const float* p[3]; };

__device__ inline u16 f2bf(float f) {
    unsigned int u = __float_as_uint(f);
    u = (u + 0x7FFFu + ((u >> 16) & 1u)) >> 16;
    return (u16)u;
}
__device__ inline float bf2f(u16 h) {
    return __uint_as_float(((unsigned int)h) << 16);
}

__device__ inline void async_load16(const void* g, void* l) {
    __builtin_amdgcn_global_load_lds(
        (const __attribute__((address_space(1))) unsigned int*)g,
        (__attribute__((address_space(3))) unsigned int*)l, 16, 0, 0);
}

// ---------------------------------------------------------------------------
// Fused weight transpose + bf16 convert: out[z][n][k] = (bf16)in_z[k][n].
// Layout: z = l*3+net for hidden layers, 9 = QWo, 10 = KWo. grid (16,16,11).
// ---------------------------------------------------------------------------
__global__ __launch_bounds__(256) void transpose_w_all(
    P11 srcs, u16* __restrict__ out)
{
    const float* in = srcs.p[blockIdx.z];
    u16* o = out + (size_t)blockIdx.z * HD * HD;
    __shared__ float tile[32][33];
    int bx = blockIdx.x * 32, by = blockIdx.y * 32;
    int tx = threadIdx.x & 31, ty = threadIdx.x >> 5;
    for (int r = ty; r < 32; r += 8)
        tile[r][tx] = in[(size_t)(by + r) * HD + bx + tx];
    __syncthreads();
    for (int r = ty; r < 32; r += 8)
        o[(size_t)(bx + r) * HD + by + tx] = f2bf(tile[tx][r]);
}

// ---------------------------------------------------------------------------
// Layer 0: H[z][row][n] = bf16(sin(sum_{k<3} X[row][k]*W0[k][n] + b0[n]))
// ---------------------------------------------------------------------------
__global__ __launch_bounds__(256) void layer0_all(
    const float* __restrict__ x, const float* __restrict__ c,
    P3 W0p, P3 b0p, u16* __restrict__ H, int net_base)
{
    int z = blockIdx.z;
    int net = net_base + z;
    const float* X  = (net == 0) ? x : c;
    const float* W0 = W0p.p[z];
    const float* b0 = b0p.p[z];
    u16* Hn = H + (size_t)z * NXR * HD;

    int idx = blockIdx.x * 256 + threadIdx.x;
    int n = idx & (HD - 1);
    int row = idx >> 9;
    float v = X[row * 3 + 0] * W0[n] + X[row * 3 + 1] * W0[HD + n] +
              X[row * 3 + 2] * W0[2 * HD + n] + b0[n];
    Hn[idx] = f2bf(__sinf(v));
}

// ---------------------------------------------------------------------------
// Multi-net bf16 MFMA GEMM (R7-exact, proven): LDS staging via
// global_load_lds, 128x128 tile, BK=32, 16x16x32 MFMA.
// ---------------------------------------------------------------------------
template<int ACT>
__global__ __launch_bounds__(256) void gemm_bt_multi(
    const u16* __restrict__ Abase, const u16* __restrict__ Wt0, size_t wstride,
    P3 bias, u16* __restrict__ Cbase)
{
    __shared__ u16 As[128 * 32];
    __shared__ u16 Bs[128 * 32];

    const int net = blockIdx.z;
    const u16* A  = Abase + (size_t)net * NXR * HD;
    const u16* Bt = Wt0 + (size_t)net * wstride;
    const float* bias_p = bias.p[net];
    u16* C = Cbase + (size_t)net * NXR * HD;

    const int tid  = threadIdx.x;
    const int wave = tid >> 6;
    const int lane = tid & 63;
    const int wr = wave >> 1, wc = wave & 1;
    const int row0 = blockIdx.x * 128;
    const int col0 = blockIdx.y * 128;

    const int lr = lane >> 2;
    const int ls = lane & 3;
    const int qm = lane & 15;
    const int qk = (lane >> 4) * 8;

    f32x4 acc[4][4] = {};

    for (int kt = 0; kt < HD; kt += 32) {
        int r0 = wave * 32 + lr;
        async_load16(A  + (size_t)(row0 + r0)      * HD + kt + ls * 8, &As[r0 * 32 + ls * 8]);
        async_load16(A  + (size_t)(row0 + r0 + 16) * HD + kt + ls * 8, &As[(r0 + 16) * 32 + ls * 8]);
        async_load16(Bt + (size_t)(col0 + r0)      * HD + kt + ls * 8, &Bs[r0 * 32 + ls * 8]);
        async_load16(Bt + (size_t)(col0 + r0 + 16) * HD + kt + ls * 8, &Bs[(r0 + 16) * 32 + ls * 8]);
        __syncthreads();

        s16x8 af[4], bfr[4];
#pragma unroll
        for (int t = 0; t < 4; ++t)
            af[t]  = *(const s16x8*)&As[(wr * 64 + t * 16 + qm) * 32 + qk];
#pragma unroll
        for (int t = 0; t < 4; ++t)
            bfr[t] = *(const s16x8*)&Bs[(wc * 64 + t * 16 + qm) * 32 + qk];
#pragma unroll
        for (int i = 0; i < 4; ++i)
#pragma unroll
            for (int j = 0; j < 4; ++j)
                acc[i][j] = __builtin_amdgcn_mfma_f32_16x16x32_bf16(af[i], bfr[j], acc[i][j], 0, 0, 0);
        __syncthreads();
    }

    const int cn = lane & 15;
    const int rq = lane >> 4;
#pragma unroll
    for (int i = 0; i < 4; ++i) {
#pragma unroll
        for (int j = 0; j < 4; ++j) {
            int gcol = col0 + wc * 64 + j * 16 + cn;
            float bv = bias_p[gcol];
#pragma unroll
            for (int r = 0; r < 4; ++r) {
                int grow = row0 + wr * 64 + i * 16 + rq * 4 + r;
                float v = acc[i][j][r] + bv;
                if (ACT) v = __sinf(v);
                C[(size_t)grow * HD + gcol] = f2bf(v);
            }
        }
    }
}

// ---------------------------------------------------------------------------
// V output layer (M=3), one wave per row, fp32 out.
// ---------------------------------------------------------------------------
__global__ __launch_bounds__(256) void vout_k(
    const u16* __restrict__ H, const float* __restrict__ Wo,
    const float* __restrict__ bo, float* __restrict__ V)
{
    int wave = threadIdx.x >> 6, lane = threadIdx.x & 63;
    int row = blockIdx.x * 4 + wave;
    s16x8 hv = *(const s16x8*)(H + (size_t)row * HD + lane * 8);
    float a0 = 0, a1 = 0, a2 = 0;
#pragma unroll
    for (int j = 0; j < 8; ++j) {
        float hf = bf2f(((const u16*)&hv)[j]);
        int k = lane * 8 + j;
        a0 += hf * Wo[k * 3 + 0];
        a1 += hf * Wo[k * 3 + 1];
        a2 += hf * Wo[k * 3 + 2];
    }
#pragma unroll
    for (int d = 32; d >= 1; d >>= 1) {
        a0 += __shfl_down(a0, d);
        a1 += __shfl_down(a1, d);
        a2 += __shfl_down(a2, d);
    }
    if (lane == 0) {
        V[row * 3 + 0] = a0 + bo[0];
        V[row * 3 + 1] = a1 + bo[1];
        V[row * 3 + 2] = a2 + bo[2];
    }
}

// ---------------------------------------------------------------------------
// Fused attention v2: out[i][c] += sum_j sigmoid(S[i][j]) * V[j][c]
// Block: 64 Q-rows x (JT=8 j-tiles of 128 cols). Q strip (64x512) staged ONCE
// in LDS (padded stride 520 -> even quad spread for ds_read_b128); K streams
// per-wave straight from global (each wave owns a 32-col strip -> K read once
// per block). NO barriers in the kt loop -> compiler pipelines K loads with
// vmcnt(N) across the fully unrolled 16 iterations.
// grid (8, 128): blockIdx.x = j-slice = XCD id (ID%8) -> 1 MB K-slice per XCD.
// ---------------------------------------------------------------------------
#define QSTR 520   // padded LDS row stride (elems): 1040 B = 65 quads (odd)
__global__ __launch_bounds__(256) void attn_mfma(
    const u16* __restrict__ Q, const u16* __restrict__ K,
    const float* __restrict__ V, float* __restrict__ out)
{
    __shared__ u16 Qs[64 * QSTR];          // 66560 B
    __shared__ float red[4][64][3];        // 3072 B cross-wave reduce

    const int tid = threadIdx.x;
    const int wave = tid >> 6, lane = tid & 63;
    const int row0 = blockIdx.y * 64;
    const int jsl  = blockIdx.x;

    const int qm = lane & 15;
    const int qk = (lane >> 4) * 8;
    const int cn = lane & 15, rq = lane >> 4;

    // ---- stage Q strip (64 rows x 512) once: flat 16B copy w/ padded rows --
    {
        const u16* qsrc = Q + (size_t)row0 * HD;
#pragma unroll
        for (int it = 0; it < 16; ++it) {
            int g16 = it * 256 + tid;            // 16B chunk id, 0..4095
            int row = g16 >> 6;                  // 64 chunks per row
            int ch  = g16 & 63;
            s16x8 v = *(const s16x8*)(qsrc + (size_t)g16 * 8);
            *(s16x8*)&Qs[row * QSTR + ch * 8] = v;
        }
    }
    __syncthreads();   // the ONLY barrier before the epilogue

    float po[4][4][3] = {};   // [i][r][c] accumulated across all j-tiles

    for (int jt = 0; jt < 8; ++jt) {
        const int col0 = (jsl * 8 + jt) * 128;
        const u16* kp = K + (size_t)(col0 + wave * 32 + qm) * HD + qk;

        // preload this tile's V rows for this wave's two 16-col subtiles
        float vv[2][3];
#pragma unroll
        for (int js = 0; js < 2; ++js) {
            size_t vr = (size_t)(col0 + wave * 32 + js * 16 + cn) * 3;
            vv[js][0] = V[vr + 0];
            vv[js][1] = V[vr + 1];
            vv[js][2] = V[vr + 2];
        }

        f32x4 acc[4][2] = {};

#pragma unroll
        for (int kt = 0; kt < 16; ++kt) {
            s16x8 b0 = *(const s16x8*)(kp + kt * 32);
            s16x8 b1 = *(const s16x8*)(kp + (size_t)16 * HD + kt * 32);
            s16x8 a[4];
#pragma unroll
            for (int t = 0; t < 4; ++t)
                a[t] = *(const s16x8*)&Qs[(t * 16 + qm) * QSTR + kt * 32 + qk];
#pragma unroll
            for (int i = 0; i < 4; ++i) {
                acc[i][0] = __builtin_amdgcn_mfma_f32_16x16x32_bf16(a[i], b0, acc[i][0], 0, 0, 0);
                acc[i][1] = __builtin_amdgcn_mfma_f32_16x16x32_bf16(a[i], b1, acc[i][1], 0, 0, 0);
            }
        }

        // sigmoid + PV accumulate (rcp = v_rcp_f32, 1 ulp)
#pragma unroll
        for (int js = 0; js < 2; ++js) {
            float v0 = vv[js][0], v1 = vv[js][1], v2 = vv[js][2];
#pragma unroll
            for (int i = 0; i < 4; ++i)
#pragma unroll
                for (int r = 0; r < 4; ++r) {
                    float s = __builtin_amdgcn_rcpf(1.f + __expf(-acc[i][js][r]));
                    po[i][r][0] += s * v0;
                    po[i][r][1] += s * v1;
                    po[i][r][2] += s * v2;
                }
        }
    }

    // ---- reduce: 16 lanes (cn) -> wave; 4 waves -> block; 1 atomic set ----
#pragma unroll
    for (int i = 0; i < 4; ++i)
#pragma unroll
        for (int r = 0; r < 4; ++r)
#pragma unroll
            for (int c = 0; c < 3; ++c) {
                float v = po[i][r][c];
                v += __shfl_down(v, 8, 16);
                v += __shfl_down(v, 4, 16);
                v += __shfl_down(v, 2, 16);
                v += __shfl_down(v, 1, 16);
                if (cn == 0)
                    red[wave][i * 16 + rq * 4 + r][c] = v;
            }
    __syncthreads();
    if (tid < 192) {
        int row = tid / 3, c = tid % 3;
        float s = red[0][row][c] + red[1][row][c] + red[2][row][c] + red[3][row][c];
        atomicAdd(&out[(size_t)(row0 + row) * 3 + c], s);
    }
}

// ---------------------------------------------------------------------------
// Workspace layouts:
//  FUSED (needs >=57 MB):  [0,6) wT | [6,30) hA (3 nets) | [30,54) hB | [54,..) Vf
//  FALLBACK (38.1 MB):     [0,6) wT | [6,22) R1 (2 nets) | [22,38) R2 | [38,..) Vf
// ---------------------------------------------------------------------------
extern "C" void kernel_launch(void* const* d_in, const int* in_sizes, int n_in,
                              void* d_out, int out_size, void* d_ws, size_t ws_size,
                              hipStream_t stream)
{
    const float* x   = (const float*)d_in[0];
    const float* c   = (const float*)d_in[1];
    const float* QW0 = (const float*)d_in[2];
    const float* Qb0 = (const float*)d_in[3];
    const float* QWh = (const float*)d_in[4];
    const float* Qbh = (const float*)d_in[5];
    const float* QWo = (const float*)d_in[6];
    const float* Qbo = (const float*)d_in[7];
    const float* KW0 = (const float*)d_in[8];
    const float* Kb0 = (const float*)d_in[9];
    const float* KWh = (const float*)d_in[10];
    const float* Kbh = (const float*)d_in[11];
    const float* KWo = (const float*)d_in[12];
    const float* Kbo = (const float*)d_in[13];
    const float* VW0 = (const float*)d_in[14];
    const float* Vb0 = (const float*)d_in[15];
    const float* VWh = (const float*)d_in[16];
    const float* Vbh = (const float*)d_in[17];
    const float* VWo = (const float*)d_in[18];
    const float* Vbo = (const float*)d_in[19];

    char* ws = (char*)d_ws;
    const size_t WTN = (size_t)HD * HD;
    const size_t MB = 1048576;
    const size_t NET = (size_t)NXR * HD;

    // ---- weight transposes (1 dispatch, both paths) ----
    u16* wT = (u16*)ws;
    P11 tsrc;
    for (int l = 0; l < 3; ++l) {
        tsrc.p[l * 3 + 0] = QWh + (size_t)l * WTN;
        tsrc.p[l * 3 + 1] = KWh + (size_t)l * WTN;
        tsrc.p[l * 3 + 2] = VWh + (size_t)l * WTN;
    }
    tsrc.p[9]  = QWo;
    tsrc.p[10] = KWo;
    transpose_w_all<<<dim3(16, 16, 11), 256, 0, stream>>>(tsrc, wT);

    const int L0G = NXR * HD / 256;  // 16384
    const u16* Qb; const u16* Kb; const float* Vf;

    if (ws_size >= 57 * MB) {
        // ================= fused path =================
        u16*   hA = (u16*)(ws + 6 * MB);
        u16*   hB = (u16*)(ws + 30 * MB);
        float* Vff = (float*)(ws + 54 * MB);

        P3 w0 = {{QW0, KW0, VW0}}, b0 = {{Qb0, Kb0, Vb0}};
        layer0_all<<<dim3(L0G, 1, 3), 256, 0, stream>>>(x, c, w0, b0, hA, 0);

        dim3 g3(NXR / 128, HD / 128, 3);
        {
            P3 b = {{Qbh + 0 * HD, Kbh + 0 * HD, Vbh + 0 * HD}};
            gemm_bt_multi<1><<<g3, 256, 0, stream>>>(hA, wT + 0 * 3 * WTN, WTN, b, hB);
        }
        {
            P3 b = {{Qbh + 1 * HD, Kbh + 1 * HD, Vbh + 1 * HD}};
            gemm_bt_multi<1><<<g3, 256, 0, stream>>>(hB, wT + 1 * 3 * WTN, WTN, b, hA);
        }
        {
            P3 b = {{Qbh + 2 * HD, Kbh + 2 * HD, Vbh + 2 * HD}};
            gemm_bt_multi<1><<<g3, 256, 0, stream>>>(hA, wT + 2 * 3 * WTN, WTN, b, hB);
        }
        {
            P3 b = {{Qbo, Kbo, nullptr}};
            gemm_bt_multi<0><<<dim3(NXR / 128, HD / 128, 2), 256, 0, stream>>>(
                hB, wT + 9 * WTN, WTN, b, hA);
        }
        vout_k<<<NCR / 4, 256, 0, stream>>>(hB + 2 * NET, VWo, Vbo, Vff);

        Qb = hA; Kb = hA + NET; Vf = Vff;
    } else {
        // ================= two-phase fallback (proven 38.1 MB) =================
        u16*   R1 = (u16*)(ws + 6 * MB);
        u16*   R2 = (u16*)(ws + 22 * MB);
        float* Vff = (float*)(ws + 38 * MB);

        {
            P3 w0 = {{VW0, nullptr, nullptr}}, b0 = {{Vb0, nullptr, nullptr}};
            layer0_all<<<dim3(L0G, 1, 1), 256, 0, stream>>>(x, c, w0, b0, R1, 2);
        }
        dim3 gv(NXR / 128, HD / 128, 1);
        {
            P3 b = {{Vbh + 0 * HD, nullptr, nullptr}};
            gemm_bt_multi<1><<<gv, 256, 0, stream>>>(R1, wT + (0 * 3 + 2) * WTN, 0, b, R2);
        }
        {
            P3 b = {{Vbh + 1 * HD, nullptr, nullptr}};
            gemm_bt_multi<1><<<gv, 256, 0, stream>>>(R2, wT + (1 * 3 + 2) * WTN, 0, b, R1);
        }
        {
            P3 b = {{Vbh + 2 * HD, nullptr, nullptr}};
            gemm_bt_multi<1><<<gv, 256, 0, stream>>>(R1, wT + (2 * 3 + 2) * WTN, 0, b, R2);
        }
        vout_k<<<NCR / 4, 256, 0, stream>>>(R2, VWo, Vbo, Vff);

        {
            P3 w0 = {{QW0, KW0, nullptr}}, b0 = {{Qb0, Kb0, nullptr}};
            layer0_all<<<dim3(L0G, 1, 2), 256, 0, stream>>>(x, c, w0, b0, R1, 0);
        }
        dim3 gqk(NXR / 128, HD / 128, 2);
        {
            P3 b = {{Qbh + 0 * HD, Kbh + 0 * HD, nullptr}};
            gemm_bt_multi<1><<<gqk, 256, 0, stream>>>(R1, wT + 0 * 3 * WTN, WTN, b, R2);
        }
        {
            P3 b = {{Qbh + 1 * HD, Kbh + 1 * HD, nullptr}};
            gemm_bt_multi<1><<<gqk, 256, 0, stream>>>(R2, wT + 1 * 3 * WTN, WTN, b, R1);
        }
        {
            P3 b = {{Qbh + 2 * HD, Kbh + 2 * HD, nullptr}};
            gemm_bt_multi<1><<<gqk, 256, 0, stream>>>(R1, wT + 2 * 3 * WTN, WTN, b, R2);
        }
        {
            P3 b = {{Qbo, Kbo, nullptr}};
            gemm_bt_multi<0><<<gqk, 256, 0, stream>>>(R2, wT + 9 * WTN, WTN, b, R1);
        }
        Qb = R1; Kb = R1 + NET; Vf = Vff;
    }

    // ---- attention ----
    hipMemsetAsync(d_out, 0, (size_t)out_size * sizeof(float), stream);
    attn_mfma<<<dim3(8, NXR / 64), 256, 0, stream>>>(Qb, Kb, Vf, (float*)d_out);
}

// Round 10
// 319.128 us; speedup vs baseline: 1.7565x; 1.3266x over previous
//
#include <hip/hip_runtime.h>
#include <math.h>

#define NXR 8192
#define NCR 8192
#define HD  512
#define NSL 8            // attention j-slices (XCD-pinned)
#define JC  (NCR / NSL)  // 1024 cols per attention block
#define KSTR 520         // padded LDS col stride (elems) -> 2-way bank aliasing only

typedef short s16x8 __attribute__((ext_vector_type(8)));
typedef float f32x4 __attribute__((ext_vector_type(4)));
typedef unsigned short u16;

struct P11 { const float* p[11]; };
struct P3  { const float* p[3]; };

__device__ inline u16 f2bf(float f) {
    unsigned int u = __float_as_uint(f);
    u = (u + 0x7FFFu + ((u >> 16) & 1u)) >> 16;
    return (u16)u;
}
__device__ inline float bf2f(u16 h) {
    return __uint_as_float(((unsigned int)h) << 16);
}

__device__ inline void async_load16(const void* g, void* l) {
    __builtin_amdgcn_global_load_lds(
        (const __attribute__((address_space(1))) unsigned int*)g,
        (__attribute__((address_space(3))) unsigned int*)l, 16, 0, 0);
}

// ---------------------------------------------------------------------------
// Fused weight transpose + bf16 convert: out[z][n][k] = (bf16)in_z[k][n].
// ---------------------------------------------------------------------------
__global__ __launch_bounds__(256) void transpose_w_all(
    P11 srcs, u16* __restrict__ out)
{
    const float* in = srcs.p[blockIdx.z];
    u16* o = out + (size_t)blockIdx.z * HD * HD;
    __shared__ float tile[32][33];
    int bx = blockIdx.x * 32, by = blockIdx.y * 32;
    int tx = threadIdx.x & 31, ty = threadIdx.x >> 5;
    for (int r = ty; r < 32; r += 8)
        tile[r][tx] = in[(size_t)(by + r) * HD + bx + tx];
    __syncthreads();
    for (int r = ty; r < 32; r += 8)
        o[(size_t)(bx + r) * HD + by + tx] = f2bf(tile[tx][r]);
}

// ---------------------------------------------------------------------------
// Layer 0: H[z][row][n] = bf16(sin(sum_{k<3} X[row][k]*W0[k][n] + b0[n]))
// ---------------------------------------------------------------------------
__global__ __launch_bounds__(256) void layer0_all(
    const float* __restrict__ x, const float* __restrict__ c,
    P3 W0p, P3 b0p, u16* __restrict__ H, int net_base)
{
    int z = blockIdx.z;
    int net = net_base + z;
    const float* X  = (net == 0) ? x : c;
    const float* W0 = W0p.p[z];
    const float* b0 = b0p.p[z];
    u16* Hn = H + (size_t)z * NXR * HD;

    int idx = blockIdx.x * 256 + threadIdx.x;
    int n = idx & (HD - 1);
    int row = idx >> 9;
    float v = X[row * 3 + 0] * W0[n] + X[row * 3 + 1] * W0[HD + n] +
              X[row * 3 + 2] * W0[2 * HD + n] + b0[n];
    Hn[idx] = f2bf(__sinf(v));
}

// ---------------------------------------------------------------------------
// Multi-net bf16 MFMA GEMM (R7-exact, proven).
// ---------------------------------------------------------------------------
template<int ACT>
__global__ __launch_bounds__(256) void gemm_bt_multi(
    const u16* __restrict__ Abase, const u16* __restrict__ Wt0, size_t wstride,
    P3 bias, u16* __restrict__ Cbase)
{
    __shared__ u16 As[128 * 32];
    __shared__ u16 Bs[128 * 32];

    const int net = blockIdx.z;
    const u16* A  = Abase + (size_t)net * NXR * HD;
    const u16* Bt = Wt0 + (size_t)net * wstride;
    const float* bias_p = bias.p[net];
    u16* C = Cbase + (size_t)net * NXR * HD;

    const int tid  = threadIdx.x;
    const int wave = tid >> 6;
    const int lane = tid & 63;
    const int wr = wave >> 1, wc = wave & 1;
    const int row0 = blockIdx.x * 128;
    const int col0 = blockIdx.y * 128;

    const int lr = lane >> 2;
    const int ls = lane & 3;
    const int qm = lane & 15;
    const int qk = (lane >> 4) * 8;

    f32x4 acc[4][4] = {};

    for (int kt = 0; kt < HD; kt += 32) {
        int r0 = wave * 32 + lr;
        async_load16(A  + (size_t)(row0 + r0)      * HD + kt + ls * 8, &As[r0 * 32 + ls * 8]);
        async_load16(A  + (size_t)(row0 + r0 + 16) * HD + kt + ls * 8, &As[(r0 + 16) * 32 + ls * 8]);
        async_load16(Bt + (size_t)(col0 + r0)      * HD + kt + ls * 8, &Bs[r0 * 32 + ls * 8]);
        async_load16(Bt + (size_t)(col0 + r0 + 16) * HD + kt + ls * 8, &Bs[(r0 + 16) * 32 + ls * 8]);
        __syncthreads();

        s16x8 af[4], bfr[4];
#pragma unroll
        for (int t = 0; t < 4; ++t)
            af[t]  = *(const s16x8*)&As[(wr * 64 + t * 16 + qm) * 32 + qk];
#pragma unroll
        for (int t = 0; t < 4; ++t)
            bfr[t] = *(const s16x8*)&Bs[(wc * 64 + t * 16 + qm) * 32 + qk];
#pragma unroll
        for (int i = 0; i < 4; ++i)
#pragma unroll
            for (int j = 0; j < 4; ++j)
                acc[i][j] = __builtin_amdgcn_mfma_f32_16x16x32_bf16(af[i], bfr[j], acc[i][j], 0, 0, 0);
        __syncthreads();
    }

    const int cn = lane & 15;
    const int rq = lane >> 4;
#pragma unroll
    for (int i = 0; i < 4; ++i) {
#pragma unroll
        for (int j = 0; j < 4; ++j) {
            int gcol = col0 + wc * 64 + j * 16 + cn;
            float bv = bias_p[gcol];
#pragma unroll
            for (int r = 0; r < 4; ++r) {
                int grow = row0 + wr * 64 + i * 16 + rq * 4 + r;
                float v = acc[i][j][r] + bv;
                if (ACT) v = __sinf(v);
                C[(size_t)grow * HD + gcol] = f2bf(v);
            }
        }
    }
}

// ---------------------------------------------------------------------------
// V output layer (M=3), one wave per row, fp32 out.
// ---------------------------------------------------------------------------
__global__ __launch_bounds__(256) void vout_k(
    const u16* __restrict__ H, const float* __restrict__ Wo,
    const float* __restrict__ bo, float* __restrict__ V)
{
    int wave = threadIdx.x >> 6, lane = threadIdx.x & 63;
    int row = blockIdx.x * 4 + wave;
    s16x8 hv = *(const s16x8*)(H + (size_t)row * HD + lane * 8);
    float a0 = 0, a1 = 0, a2 = 0;
#pragma unroll
    for (int j = 0; j < 8; ++j) {
        float hf = bf2f(((const u16*)&hv)[j]);
        int k = lane * 8 + j;
        a0 += hf * Wo[k * 3 + 0];
        a1 += hf * Wo[k * 3 + 1];
        a2 += hf * Wo[k * 3 + 2];
    }
#pragma unroll
    for (int d = 32; d >= 1; d >>= 1) {
        a0 += __shfl_down(a0, d);
        a1 += __shfl_down(a1, d);
        a2 += __shfl_down(a2, d);
    }
    if (lane == 0) {
        V[row * 3 + 0] = a0 + bo[0];
        V[row * 3 + 1] = a1 + bo[1];
        V[row * 3 + 2] = a2 + bo[2];
    }
}

// ---------------------------------------------------------------------------
// Fused attention v3: Q-in-registers, K-in-LDS.
// Block = 64 Q-rows x JC=1024 cols. Wave w owns rows w*16..w*16+16, whose
// MFMA A-fragments for ALL of K=512 are exactly 16 s16x8 = 64 VGPRs, loaded
// ONCE. j-loop stages K tiles (32 cols x 512, padded stride 520) in LDS,
// shared by all 4 waves. Inner kt loop: 2 ds_read_b128 + 2 MFMA, no global,
// no barriers. 2 barriers per 32-col tile (amortized over 32 MFMAs/wave).
// ~112 VGPR -> 4 waves/SIMD; 33.3 KB LDS -> 4 blocks/CU: ~16 waves/CU.
// grid (NSL=8, 128): blockIdx.x = jslice = XCD id -> K slice L2-local.
// ---------------------------------------------------------------------------
__global__ __launch_bounds__(256) void attn_mfma(
    const u16* __restrict__ Q, const u16* __restrict__ K,
    const float* __restrict__ V, float* __restrict__ out)
{
    __shared__ u16 Ks[32 * KSTR];   // 33,280 B

    const int tid = threadIdx.x;
    const int wave = tid >> 6, lane = tid & 63;
    const int row0 = blockIdx.y * 64;
    const int col_base = blockIdx.x * JC;

    const int qm = lane & 15;   // A: row-in-16; B/C: col-in-16
    const int g  = lane >> 4;   // k-half group 0..3 (k = ...*32 + g*8)

    // ---- Q fragments for the whole kernel: 16 x s16x8 = 64 VGPRs ----
    s16x8 qf[16];
    {
        const u16* qp = Q + (size_t)(row0 + wave * 16 + qm) * HD + g * 8;
#pragma unroll
        for (int t = 0; t < 16; ++t)
            qf[t] = *(const s16x8*)(qp + t * 32);
    }

    float po[4][3] = {};   // rows g*4+r of this wave's 16 rows, accumulated over all j

    for (int jt = 0; jt < JC / 32; ++jt) {
        const int col0 = col_base + jt * 32;

        // ---- stage K tile [32 cols][512] into LDS (padded stride) ----
#pragma unroll
        for (int i = 0; i < 8; ++i) {
            int chunk = i * 256 + tid;          // 0..2047
            int cc = chunk >> 6;                // col 0..31
            int ch = chunk & 63;                // 16B chunk within row
            s16x8 v = *(const s16x8*)(K + (size_t)(col0 + cc) * HD + ch * 8);
            *(s16x8*)&Ks[cc * KSTR + ch * 8] = v;
        }
        __syncthreads();

        // V rows for this tile (L2/L3-hot; hidden behind kt loop)
        float vv[2][3];
#pragma unroll
        for (int ct = 0; ct < 2; ++ct) {
            size_t vr = (size_t)(col0 + ct * 16 + qm) * 3;
            vv[ct][0] = V[vr + 0];
            vv[ct][1] = V[vr + 1];
            vv[ct][2] = V[vr + 2];
        }

        f32x4 acc[2] = {};
#pragma unroll
        for (int kt = 0; kt < 16; ++kt) {
            s16x8 b0 = *(const s16x8*)&Ks[qm * KSTR + kt * 32 + g * 8];
            s16x8 b1 = *(const s16x8*)&Ks[(16 + qm) * KSTR + kt * 32 + g * 8];
            acc[0] = __builtin_amdgcn_mfma_f32_16x16x32_bf16(qf[kt], b0, acc[0], 0, 0, 0);
            acc[1] = __builtin_amdgcn_mfma_f32_16x16x32_bf16(qf[kt], b1, acc[1], 0, 0, 0);
        }

        // sigmoid + PV (rcp = v_rcp_f32, 1 ulp)
#pragma unroll
        for (int ct = 0; ct < 2; ++ct) {
#pragma unroll
            for (int r = 0; r < 4; ++r) {
                float s = __builtin_amdgcn_rcpf(1.f + __expf(-acc[ct][r]));
                po[r][0] += s * vv[ct][0];
                po[r][1] += s * vv[ct][1];
                po[r][2] += s * vv[ct][2];
            }
        }
        __syncthreads();   // Ks reused next tile
    }

    // ---- reduce over the 16 col-lanes; rows are wave-private ----
#pragma unroll
    for (int r = 0; r < 4; ++r)
#pragma unroll
        for (int c = 0; c < 3; ++c) {
            float v = po[r][c];
            v += __shfl_down(v, 8, 16);
            v += __shfl_down(v, 4, 16);
            v += __shfl_down(v, 2, 16);
            v += __shfl_down(v, 1, 16);
            if (qm == 0)
                atomicAdd(&out[(size_t)(row0 + wave * 16 + g * 4 + r) * 3 + c], v);
        }
}

// ---------------------------------------------------------------------------
// Workspace layouts:
//  FUSED (needs >=57 MB):  [0,6) wT | [6,30) hA (3 nets) | [30,54) hB | [54,..) Vf
//  FALLBACK (38.1 MB):     [0,6) wT | [6,22) R1 (2 nets) | [22,38) R2 | [38,..) Vf
// ---------------------------------------------------------------------------
extern "C" void kernel_launch(void* const* d_in, const int* in_sizes, int n_in,
                              void* d_out, int out_size, void* d_ws, size_t ws_size,
                              hipStream_t stream)
{
    const float* x   = (const float*)d_in[0];
    const float* c   = (const float*)d_in[1];
    const float* QW0 = (const float*)d_in[2];
    const float* Qb0 = (const float*)d_in[3];
    const float* QWh = (const float*)d_in[4];
    const float* Qbh = (const float*)d_in[5];
    const float* QWo = (const float*)d_in[6];
    const float* Qbo = (const float*)d_in[7];
    const float* KW0 = (const float*)d_in[8];
    const float* Kb0 = (const float*)d_in[9];
    const float* KWh = (const float*)d_in[10];
    const float* Kbh = (const float*)d_in[11];
    const float* KWo = (const float*)d_in[12];
    const float* Kbo = (const float*)d_in[13];
    const float* VW0 = (const float*)d_in[14];
    const float* Vb0 = (const float*)d_in[15];
    const float* VWh = (const float*)d_in[16];
    const float* Vbh = (const float*)d_in[17];
    const float* VWo = (const float*)d_in[18];
    const float* Vbo = (const float*)d_in[19];

    char* ws = (char*)d_ws;
    const size_t WTN = (size_t)HD * HD;
    const size_t MB = 1048576;
    const size_t NET = (size_t)NXR * HD;

    // ---- weight transposes (1 dispatch, both paths) ----
    u16* wT = (u16*)ws;
    P11 tsrc;
    for (int l = 0; l < 3; ++l) {
        tsrc.p[l * 3 + 0] = QWh + (size_t)l * WTN;
        tsrc.p[l * 3 + 1] = KWh + (size_t)l * WTN;
        tsrc.p[l * 3 + 2] = VWh + (size_t)l * WTN;
    }
    tsrc.p[9]  = QWo;
    tsrc.p[10] = KWo;
    transpose_w_all<<<dim3(16, 16, 11), 256, 0, stream>>>(tsrc, wT);

    const int L0G = NXR * HD / 256;  // 16384
    const u16* Qb; const u16* Kb; const float* Vf;

    if (ws_size >= 57 * MB) {
        // ================= fused path =================
        u16*   hA = (u16*)(ws + 6 * MB);
        u16*   hB = (u16*)(ws + 30 * MB);
        float* Vff = (float*)(ws + 54 * MB);

        P3 w0 = {{QW0, KW0, VW0}}, b0 = {{Qb0, Kb0, Vb0}};
        layer0_all<<<dim3(L0G, 1, 3), 256, 0, stream>>>(x, c, w0, b0, hA, 0);

        dim3 g3(NXR / 128, HD / 128, 3);
        {
            P3 b = {{Qbh + 0 * HD, Kbh + 0 * HD, Vbh + 0 * HD}};
            gemm_bt_multi<1><<<g3, 256, 0, stream>>>(hA, wT + 0 * 3 * WTN, WTN, b, hB);
        }
        {
            P3 b = {{Qbh + 1 * HD, Kbh + 1 * HD, Vbh + 1 * HD}};
            gemm_bt_multi<1><<<g3, 256, 0, stream>>>(hB, wT + 1 * 3 * WTN, WTN, b, hA);
        }
        {
            P3 b = {{Qbh + 2 * HD, Kbh + 2 * HD, Vbh + 2 * HD}};
            gemm_bt_multi<1><<<g3, 256, 0, stream>>>(hA, wT + 2 * 3 * WTN, WTN, b, hB);
        }
        {
            P3 b = {{Qbo, Kbo, nullptr}};
            gemm_bt_multi<0><<<dim3(NXR / 128, HD / 128, 2), 256, 0, stream>>>(
                hB, wT + 9 * WTN, WTN, b, hA);
        }
        vout_k<<<NCR / 4, 256, 0, stream>>>(hB + 2 * NET, VWo, Vbo, Vff);

        Qb = hA; Kb = hA + NET; Vf = Vff;
    } else {
        // ================= two-phase fallback (proven 38.1 MB) =================
        u16*   R1 = (u16*)(ws + 6 * MB);
        u16*   R2 = (u16*)(ws + 22 * MB);
        float* Vff = (float*)(ws + 38 * MB);

        {
            P3 w0 = {{VW0, nullptr, nullptr}}, b0 = {{Vb0, nullptr, nullptr}};
            layer0_all<<<dim3(L0G, 1, 1), 256, 0, stream>>>(x, c, w0, b0, R1, 2);
        }
        dim3 gv(NXR / 128, HD / 128, 1);
        {
            P3 b = {{Vbh + 0 * HD, nullptr, nullptr}};
            gemm_bt_multi<1><<<gv, 256, 0, stream>>>(R1, wT + (0 * 3 + 2) * WTN, 0, b, R2);
        }
        {
            P3 b = {{Vbh + 1 * HD, nullptr, nullptr}};
            gemm_bt_multi<1><<<gv, 256, 0, stream>>>(R2, wT + (1 * 3 + 2) * WTN, 0, b, R1);
        }
        {
            P3 b = {{Vbh + 2 * HD, nullptr, nullptr}};
            gemm_bt_multi<1><<<gv, 256, 0, stream>>>(R1, wT + (2 * 3 + 2) * WTN, 0, b, R2);
        }
        vout_k<<<NCR / 4, 256, 0, stream>>>(R2, VWo, Vbo, Vff);

        {
            P3 w0 = {{QW0, KW0, nullptr}}, b0 = {{Qb0, Kb0, nullptr}};
            layer0_all<<<dim3(L0G, 1, 2), 256, 0, stream>>>(x, c, w0, b0, R1, 0);
        }
        dim3 gqk(NXR / 128, HD / 128, 2);
        {
            P3 b = {{Qbh + 0 * HD, Kbh + 0 * HD, nullptr}};
            gemm_bt_multi<1><<<gqk, 256, 0, stream>>>(R1, wT + 0 * 3 * WTN, WTN, b, R2);
        }
        {
            P3 b = {{Qbh + 1 * HD, Kbh + 1 * HD, nullptr}};
            gemm_bt_multi<1><<<gqk, 256, 0, stream>>>(R2, wT + 1 * 3 * WTN, WTN, b, R1);
        }
        {
            P3 b = {{Qbh + 2 * HD, Kbh + 2 * HD, nullptr}};
            gemm_bt_multi<1><<<gqk, 256, 0, stream>>>(R1, wT + 2 * 3 * WTN, WTN, b, R2);
        }
        {
            P3 b = {{Qbo, Kbo, nullptr}};
            gemm_bt_multi<0><<<gqk, 256, 0, stream>>>(R2, wT + 9 * WTN, WTN, b, R1);
        }
        Qb = R1; Kb = R1 + NET; Vf = Vff;
    }

    // ---- attention ----
    hipMemsetAsync(d_out, 0, (size_t)out_size * sizeof(float), stream);
    attn_mfma<<<dim3(NSL, NXR / 64), 256, 0, stream>>>(Qb, Kb, Vf, (float*)d_out);
}

// Round 11
// 314.897 us; speedup vs baseline: 1.7801x; 1.0134x over previous
//
#include <hip/hip_runtime.h>
#include <math.h>

#define NXR 8192
#define NCR 8192
#define HD  512
#define NSL 8            // attention j-slices (XCD-pinned)
#define JC  (NCR / NSL)  // 1024 cols per attention block
#define KSTR 520         // padded LDS col stride (elems); b128 reads are bank-balanced

typedef short s16x8 __attribute__((ext_vector_type(8)));
typedef float f32x4 __attribute__((ext_vector_type(4)));
typedef unsigned short u16;

struct P11 { const float* p[11]; };
struct P3  { const float* p[3]; };

__device__ inline u16 f2bf(float f) {
    unsigned int u = __float_as_uint(f);
    u = (u + 0x7FFFu + ((u >> 16) & 1u)) >> 16;
    return (u16)u;
}
__device__ inline float bf2f(u16 h) {
    return __uint_as_float(((unsigned int)h) << 16);
}

// ---------------------------------------------------------------------------
// Fused weight transpose + bf16 convert: out[z][n][k] = (bf16)in_z[k][n].
// ---------------------------------------------------------------------------
__global__ __launch_bounds__(256) void transpose_w_all(
    P11 srcs, u16* __restrict__ out)
{
    const float* in = srcs.p[blockIdx.z];
    u16* o = out + (size_t)blockIdx.z * HD * HD;
    __shared__ float tile[32][33];
    int bx = blockIdx.x * 32, by = blockIdx.y * 32;
    int tx = threadIdx.x & 31, ty = threadIdx.x >> 5;
    for (int r = ty; r < 32; r += 8)
        tile[r][tx] = in[(size_t)(by + r) * HD + bx + tx];
    __syncthreads();
    for (int r = ty; r < 32; r += 8)
        o[(size_t)(bx + r) * HD + by + tx] = f2bf(tile[tx][r]);
}

// ---------------------------------------------------------------------------
// Layer 0: H[z][row][n] = bf16(sin(sum_{k<3} X[row][k]*W0[k][n] + b0[n]))
// ---------------------------------------------------------------------------
__global__ __launch_bounds__(256) void layer0_all(
    const float* __restrict__ x, const float* __restrict__ c,
    P3 W0p, P3 b0p, u16* __restrict__ H, int net_base)
{
    int z = blockIdx.z;
    int net = net_base + z;
    const float* X  = (net == 0) ? x : c;
    const float* W0 = W0p.p[z];
    const float* b0 = b0p.p[z];
    u16* Hn = H + (size_t)z * NXR * HD;

    int idx = blockIdx.x * 256 + threadIdx.x;
    int n = idx & (HD - 1);
    int row = idx >> 9;
    float v = X[row * 3 + 0] * W0[n] + X[row * 3 + 1] * W0[HD + n] +
              X[row * 3 + 2] * W0[2 * HD + n] + b0[n];
    Hn[idx] = f2bf(__sinf(v));
}

// ---------------------------------------------------------------------------
// GEMM v2 (A-in-registers, W-in-LDS; attn-v3-proven skeleton, 32 rows/wave):
// C[net] = act(A[net] @ Wt[net]^T + bias[net]).
// Block = 128 rows x 256 cols; wave holds 32 A-rows in regs (qf[16][2]).
// Col-loop: stage 32-col W tile in LDS; kt-loop: 2 ds_read_b128 + 4 MFMA,
// no barriers inside; 2 barriers per col-tile. grid (64, 2, z).
// ---------------------------------------------------------------------------
template<int ACT>
__global__ __launch_bounds__(256) void gemm_rs(
    const u16* __restrict__ Abase, const u16* __restrict__ Wt0, size_t wstride,
    P3 bias, u16* __restrict__ Cbase)
{
    __shared__ u16 Ws[32 * KSTR];   // 33,280 B

    const int net = blockIdx.z;
    const u16* A  = Abase + (size_t)net * NXR * HD;
    const u16* Wt = Wt0 + (size_t)net * wstride;
    const float* bias_p = bias.p[net];
    u16* C = Cbase + (size_t)net * NXR * HD;

    const int tid = threadIdx.x;
    const int wave = tid >> 6, lane = tid & 63;
    const int row0 = blockIdx.x * 128;
    const int colbase = blockIdx.y * 256;

    const int qm = lane & 15;
    const int g  = lane >> 4;

    // A fragments for this wave's 32 rows, all K: 32 x s16x8 = 128 VGPRs.
    s16x8 qf[16][2];
    {
        const u16* ap = A + (size_t)(row0 + wave * 32 + qm) * HD + g * 8;
#pragma unroll
        for (int t = 0; t < 16; ++t) {
            qf[t][0] = *(const s16x8*)(ap + t * 32);
            qf[t][1] = *(const s16x8*)(ap + (size_t)16 * HD + t * 32);
        }
    }

    for (int ct = 0; ct < 8; ++ct) {
        const int col0 = colbase + ct * 32;

        // stage W tile [32 cols][512] into LDS
#pragma unroll
        for (int i = 0; i < 8; ++i) {
            int chunk = i * 256 + tid;
            int cc = chunk >> 6;
            int ch = chunk & 63;
            s16x8 v = *(const s16x8*)(Wt + (size_t)(col0 + cc) * HD + ch * 8);
            *(s16x8*)&Ws[cc * KSTR + ch * 8] = v;
        }
        __syncthreads();

        f32x4 acc[2][2] = {};
#pragma unroll
        for (int kt = 0; kt < 16; ++kt) {
            s16x8 b0 = *(const s16x8*)&Ws[qm * KSTR + kt * 32 + g * 8];
            s16x8 b1 = *(const s16x8*)&Ws[(16 + qm) * KSTR + kt * 32 + g * 8];
            acc[0][0] = __builtin_amdgcn_mfma_f32_16x16x32_bf16(qf[kt][0], b0, acc[0][0], 0, 0, 0);
            acc[0][1] = __builtin_amdgcn_mfma_f32_16x16x32_bf16(qf[kt][0], b1, acc[0][1], 0, 0, 0);
            acc[1][0] = __builtin_amdgcn_mfma_f32_16x16x32_bf16(qf[kt][1], b0, acc[1][0], 0, 0, 0);
            acc[1][1] = __builtin_amdgcn_mfma_f32_16x16x32_bf16(qf[kt][1], b1, acc[1][1], 0, 0, 0);
        }

        // epilogue: bias + act + bf16 store (C/D: col=lane&15, row=g*4+r)
        float bv0 = bias_p[col0 + qm];
        float bv1 = bias_p[col0 + 16 + qm];
#pragma unroll
        for (int h = 0; h < 2; ++h) {
#pragma unroll
            for (int r = 0; r < 4; ++r) {
                int grow = row0 + wave * 32 + h * 16 + g * 4 + r;
                float v0 = acc[h][0][r] + bv0;
                float v1 = acc[h][1][r] + bv1;
                if (ACT) { v0 = __sinf(v0); v1 = __sinf(v1); }
                C[(size_t)grow * HD + col0 + qm]      = f2bf(v0);
                C[(size_t)grow * HD + col0 + 16 + qm] = f2bf(v1);
            }
        }
        __syncthreads();
    }
}

// ---------------------------------------------------------------------------
// V output layer (M=3), one wave per row, fp32 out.
// ---------------------------------------------------------------------------
__global__ __launch_bounds__(256) void vout_k(
    const u16* __restrict__ H, const float* __restrict__ Wo,
    const float* __restrict__ bo, float* __restrict__ V)
{
    int wave = threadIdx.x >> 6, lane = threadIdx.x & 63;
    int row = blockIdx.x * 4 + wave;
    s16x8 hv = *(const s16x8*)(H + (size_t)row * HD + lane * 8);
    float a0 = 0, a1 = 0, a2 = 0;
#pragma unroll
    for (int j = 0; j < 8; ++j) {
        float hf = bf2f(((const u16*)&hv)[j]);
        int k = lane * 8 + j;
        a0 += hf * Wo[k * 3 + 0];
        a1 += hf * Wo[k * 3 + 1];
        a2 += hf * Wo[k * 3 + 2];
    }
#pragma unroll
    for (int d = 32; d >= 1; d >>= 1) {
        a0 += __shfl_down(a0, d);
        a1 += __shfl_down(a1, d);
        a2 += __shfl_down(a2, d);
    }
    if (lane == 0) {
        V[row * 3 + 0] = a0 + bo[0];
        V[row * 3 + 1] = a1 + bo[1];
        V[row * 3 + 2] = a2 + bo[2];
    }
}

// ---------------------------------------------------------------------------
// Fused attention v4: Q-in-registers (32 rows/wave), K-in-LDS.
// Block = 128 Q-rows x JC=1024 cols; wave w holds rows w*32..w*32+31
// (qf[16][2] = 128 VGPRs). Inner kt loop: 2 ds_read_b128 feed 4 MFMAs
// (halves LDS-per-FLOP vs v3, which was LDS-pipe-bound 3:1).
// grid (NSL=8, 64) = 512 blocks = exact 2/CU fill.
// ---------------------------------------------------------------------------
__global__ __launch_bounds__(256) void attn_mfma(
    const u16* __restrict__ Q, const u16* __restrict__ K,
    const float* __restrict__ V, float* __restrict__ out)
{
    __shared__ u16 Ks[32 * KSTR];   // 33,280 B

    const int tid = threadIdx.x;
    const int wave = tid >> 6, lane = tid & 63;
    const int row0 = blockIdx.y * 128;
    const int col_base = blockIdx.x * JC;

    const int qm = lane & 15;
    const int g  = lane >> 4;

    // Q fragments: 32 rows x all K = 32 x s16x8 = 128 VGPRs, loaded once.
    s16x8 qf[16][2];
    {
        const u16* qp = Q + (size_t)(row0 + wave * 32 + qm) * HD + g * 8;
#pragma unroll
        for (int t = 0; t < 16; ++t) {
            qf[t][0] = *(const s16x8*)(qp + t * 32);
            qf[t][1] = *(const s16x8*)(qp + (size_t)16 * HD + t * 32);
        }
    }

    float po[2][4][3] = {};   // [rowfrag][r][c], accumulated over all j

    for (int jt = 0; jt < JC / 32; ++jt) {
        const int col0 = col_base + jt * 32;

        // stage K tile [32 cols][512] into LDS
#pragma unroll
        for (int i = 0; i < 8; ++i) {
            int chunk = i * 256 + tid;
            int cc = chunk >> 6;
            int ch = chunk & 63;
            s16x8 v = *(const s16x8*)(K + (size_t)(col0 + cc) * HD + ch * 8);
            *(s16x8*)&Ks[cc * KSTR + ch * 8] = v;
        }
        __syncthreads();

        // V rows for this tile
        float vv[2][3];
#pragma unroll
        for (int ct = 0; ct < 2; ++ct) {
            size_t vr = (size_t)(col0 + ct * 16 + qm) * 3;
            vv[ct][0] = V[vr + 0];
            vv[ct][1] = V[vr + 1];
            vv[ct][2] = V[vr + 2];
        }

        f32x4 acc[2][2] = {};
#pragma unroll
        for (int kt = 0; kt < 16; ++kt) {
            s16x8 b0 = *(const s16x8*)&Ks[qm * KSTR + kt * 32 + g * 8];
            s16x8 b1 = *(const s16x8*)&Ks[(16 + qm) * KSTR + kt * 32 + g * 8];
            acc[0][0] = __builtin_amdgcn_mfma_f32_16x16x32_bf16(qf[kt][0], b0, acc[0][0], 0, 0, 0);
            acc[0][1] = __builtin_amdgcn_mfma_f32_16x16x32_bf16(qf[kt][0], b1, acc[0][1], 0, 0, 0);
            acc[1][0] = __builtin_amdgcn_mfma_f32_16x16x32_bf16(qf[kt][1], b0, acc[1][0], 0, 0, 0);
            acc[1][1] = __builtin_amdgcn_mfma_f32_16x16x32_bf16(qf[kt][1], b1, acc[1][1], 0, 0, 0);
        }

        // sigmoid + PV (rcp = v_rcp_f32, 1 ulp)
#pragma unroll
        for (int h = 0; h < 2; ++h)
#pragma unroll
            for (int ct = 0; ct < 2; ++ct)
#pragma unroll
                for (int r = 0; r < 4; ++r) {
                    float s = __builtin_amdgcn_rcpf(1.f + __expf(-acc[h][ct][r]));
                    po[h][r][0] += s * vv[ct][0];
                    po[h][r][1] += s * vv[ct][1];
                    po[h][r][2] += s * vv[ct][2];
                }
        __syncthreads();   // Ks reused next tile
    }

    // reduce over the 16 col-lanes; rows are wave-private
#pragma unroll
    for (int h = 0; h < 2; ++h)
#pragma unroll
        for (int r = 0; r < 4; ++r)
#pragma unroll
            for (int c = 0; c < 3; ++c) {
                float v = po[h][r][c];
                v += __shfl_down(v, 8, 16);
                v += __shfl_down(v, 4, 16);
                v += __shfl_down(v, 2, 16);
                v += __shfl_down(v, 1, 16);
                if (qm == 0)
                    atomicAdd(&out[(size_t)(row0 + wave * 32 + h * 16 + g * 4 + r) * 3 + c], v);
            }
}

// ---------------------------------------------------------------------------
// Workspace layouts:
//  FUSED (needs >=57 MB):  [0,6) wT | [6,30) hA (3 nets) | [30,54) hB | [54,..) Vf
//  FALLBACK (38.1 MB):     [0,6) wT | [6,22) R1 (2 nets) | [22,38) R2 | [38,..) Vf
// ---------------------------------------------------------------------------
extern "C" void kernel_launch(void* const* d_in, const int* in_sizes, int n_in,
                              void* d_out, int out_size, void* d_ws, size_t ws_size,
                              hipStream_t stream)
{
    const float* x   = (const float*)d_in[0];
    const float* c   = (const float*)d_in[1];
    const float* QW0 = (const float*)d_in[2];
    const float* Qb0 = (const float*)d_in[3];
    const float* QWh = (const float*)d_in[4];
    const float* Qbh = (const float*)d_in[5];
    const float* QWo = (const float*)d_in[6];
    const float* Qbo = (const float*)d_in[7];
    const float* KW0 = (const float*)d_in[8];
    const float* Kb0 = (const float*)d_in[9];
    const float* KWh = (const float*)d_in[10];
    const float* Kbh = (const float*)d_in[11];
    const float* KWo = (const float*)d_in[12];
    const float* Kbo = (const float*)d_in[13];
    const float* VW0 = (const float*)d_in[14];
    const float* Vb0 = (const float*)d_in[15];
    const float* VWh = (const float*)d_in[16];
    const float* Vbh = (const float*)d_in[17];
    const float* VWo = (const float*)d_in[18];
    const float* Vbo = (const float*)d_in[19];

    char* ws = (char*)d_ws;
    const size_t WTN = (size_t)HD * HD;
    const size_t MB = 1048576;
    const size_t NET = (size_t)NXR * HD;

    // ---- weight transposes (1 dispatch, both paths) ----
    u16* wT = (u16*)ws;
    P11 tsrc;
    for (int l = 0; l < 3; ++l) {
        tsrc.p[l * 3 + 0] = QWh + (size_t)l * WTN;
        tsrc.p[l * 3 + 1] = KWh + (size_t)l * WTN;
        tsrc.p[l * 3 + 2] = VWh + (size_t)l * WTN;
    }
    tsrc.p[9]  = QWo;
    tsrc.p[10] = KWo;
    transpose_w_all<<<dim3(16, 16, 11), 256, 0, stream>>>(tsrc, wT);

    const int L0G = NXR * HD / 256;  // 16384
    const u16* Qb; const u16* Kb; const float* Vf;

    if (ws_size >= 57 * MB) {
        // ================= fused path =================
        u16*   hA = (u16*)(ws + 6 * MB);
        u16*   hB = (u16*)(ws + 30 * MB);
        float* Vff = (float*)(ws + 54 * MB);

        P3 w0 = {{QW0, KW0, VW0}}, b0 = {{Qb0, Kb0, Vb0}};
        layer0_all<<<dim3(L0G, 1, 3), 256, 0, stream>>>(x, c, w0, b0, hA, 0);

        dim3 g3(NXR / 128, 2, 3);
        {
            P3 b = {{Qbh + 0 * HD, Kbh + 0 * HD, Vbh + 0 * HD}};
            gemm_rs<1><<<g3, 256, 0, stream>>>(hA, wT + 0 * 3 * WTN, WTN, b, hB);
        }
        {
            P3 b = {{Qbh + 1 * HD, Kbh + 1 * HD, Vbh + 1 * HD}};
            gemm_rs<1><<<g3, 256, 0, stream>>>(hB, wT + 1 * 3 * WTN, WTN, b, hA);
        }
        {
            P3 b = {{Qbh + 2 * HD, Kbh + 2 * HD, Vbh + 2 * HD}};
            gemm_rs<1><<<g3, 256, 0, stream>>>(hA, wT + 2 * 3 * WTN, WTN, b, hB);
        }
        {
            P3 b = {{Qbo, Kbo, nullptr}};
            gemm_rs<0><<<dim3(NXR / 128, 2, 2), 256, 0, stream>>>(
                hB, wT + 9 * WTN, WTN, b, hA);
        }
        vout_k<<<NCR / 4, 256, 0, stream>>>(hB + 2 * NET, VWo, Vbo, Vff);

        Qb = hA; Kb = hA + NET; Vf = Vff;
    } else {
        // ================= two-phase fallback (proven 38.1 MB) =================
        u16*   R1 = (u16*)(ws + 6 * MB);
        u16*   R2 = (u16*)(ws + 22 * MB);
        float* Vff = (float*)(ws + 38 * MB);

        {
            P3 w0 = {{VW0, nullptr, nullptr}}, b0 = {{Vb0, nullptr, nullptr}};
            layer0_all<<<dim3(L0G, 1, 1), 256, 0, stream>>>(x, c, w0, b0, R1, 2);
        }
        dim3 gv(NXR / 128, 2, 1);
        {
            P3 b = {{Vbh + 0 * HD, nullptr, nullptr}};
            gemm_rs<1><<<gv, 256, 0, stream>>>(R1, wT + (0 * 3 + 2) * WTN, 0, b, R2);
        }
        {
            P3 b = {{Vbh + 1 * HD, nullptr, nullptr}};
            gemm_rs<1><<<gv, 256, 0, stream>>>(R2, wT + (1 * 3 + 2) * WTN, 0, b, R1);
        }
        {
            P3 b = {{Vbh + 2 * HD, nullptr, nullptr}};
            gemm_rs<1><<<gv, 256, 0, stream>>>(R1, wT + (2 * 3 + 2) * WTN, 0, b, R2);
        }
        vout_k<<<NCR / 4, 256, 0, stream>>>(R2, VWo, Vbo, Vff);

        {
            P3 w0 = {{QW0, KW0, nullptr}}, b0 = {{Qb0, Kb0, nullptr}};
            layer0_all<<<dim3(L0G, 1, 2), 256, 0, stream>>>(x, c, w0, b0, R1, 0);
        }
        dim3 gqk(NXR / 128, 2, 2);
        {
            P3 b = {{Qbh + 0 * HD, Kbh + 0 * HD, nullptr}};
            gemm_rs<1><<<gqk, 256, 0, stream>>>(R1, wT + 0 * 3 * WTN, WTN, b, R2);
        }
        {
            P3 b = {{Qbh + 1 * HD, Kbh + 1 * HD, nullptr}};
            gemm_rs<1><<<gqk, 256, 0, stream>>>(R2, wT + 1 * 3 * WTN, WTN, b, R1);
        }
        {
            P3 b = {{Qbh + 2 * HD, Kbh + 2 * HD, nullptr}};
            gemm_rs<1><<<gqk, 256, 0, stream>>>(R1, wT + 2 * 3 * WTN, WTN, b, R2);
        }
        {
            P3 b = {{Qbo, Kbo, nullptr}};
            gemm_rs<0><<<gqk, 256, 0, stream>>>(R2, wT + 9 * WTN, WTN, b, R1);
        }
        Qb = R1; Kb = R1 + NET; Vf = Vff;
    }

    // ---- attention ----
    hipMemsetAsync(d_out, 0, (size_t)out_size * sizeof(float), stream);
    attn_mfma<<<dim3(NSL, NXR / 128), 256, 0, stream>>>(Qb, Kb, Vf, (float*)d_out);
}

// Round 12
// 306.331 us; speedup vs baseline: 1.8299x; 1.0280x over previous
//
#include <hip/hip_runtime.h>
#include <math.h>

#define NXR 8192
#define NCR 8192
#define HD  512
#define NSL 16           // attention j-slices
#define JC  (NCR / NSL)  // 512 cols per attention block
#define KSTR 520         // padded LDS col stride (elems)

typedef short s16x8 __attribute__((ext_vector_type(8)));
typedef float f32x4 __attribute__((ext_vector_type(4)));
typedef unsigned short u16;

struct P11 { const float* p[11]; };
struct P3  { const float* p[3]; };

__device__ inline u16 f2bf(float f) {
    unsigned int u = __float_as_uint(f);
    u = (u + 0x7FFFu + ((u >> 16) & 1u)) >> 16;
    return (u16)u;
}
__device__ inline float bf2f(u16 h) {
    return __uint_as_float(((unsigned int)h) << 16);
}

// ---------------------------------------------------------------------------
// Fused weight transpose + bf16 convert: out[z][n][k] = (bf16)in_z[k][n].
// ---------------------------------------------------------------------------
__global__ __launch_bounds__(256) void transpose_w_all(
    P11 srcs, u16* __restrict__ out)
{
    const float* in = srcs.p[blockIdx.z];
    u16* o = out + (size_t)blockIdx.z * HD * HD;
    __shared__ float tile[32][33];
    int bx = blockIdx.x * 32, by = blockIdx.y * 32;
    int tx = threadIdx.x & 31, ty = threadIdx.x >> 5;
    for (int r = ty; r < 32; r += 8)
        tile[r][tx] = in[(size_t)(by + r) * HD + bx + tx];
    __syncthreads();
    for (int r = ty; r < 32; r += 8)
        o[(size_t)(bx + r) * HD + by + tx] = f2bf(tile[tx][r]);
}

// ---------------------------------------------------------------------------
// Layer 0, 8 outputs/thread: H[z][row][n..n+7] = sin(x.W0 + b0), bf16x8 store.
// grid (NXR*HD/2048, 1, nz)
// ---------------------------------------------------------------------------
__global__ __launch_bounds__(256) void layer0_all(
    const float* __restrict__ x, const float* __restrict__ c,
    P3 W0p, P3 b0p, u16* __restrict__ H, int net_base)
{
    int z = blockIdx.z;
    int net = net_base + z;
    const float* X  = (net == 0) ? x : c;
    const float* W0 = W0p.p[z];
    const float* b0 = b0p.p[z];
    u16* Hn = H + (size_t)z * NXR * HD;

    int idx = (blockIdx.x * 256 + threadIdx.x) * 8;
    int n = idx & (HD - 1);
    int row = idx >> 9;
    float x0 = X[row * 3 + 0], x1 = X[row * 3 + 1], x2 = X[row * 3 + 2];
    s16x8 o;
#pragma unroll
    for (int j = 0; j < 8; ++j) {
        float v = x0 * W0[n + j] + x1 * W0[HD + n + j] + x2 * W0[2 * HD + n + j] + b0[n + j];
        ((u16*)&o)[j] = f2bf(__sinf(v));
    }
    *(s16x8*)&Hn[idx] = o;
}

// ---------------------------------------------------------------------------
// GEMM v3 (A-in-registers, W-in-LDS): C[net] = act(A[net]@Wt[net]^T + bias).
// Block = 128 rows x 128 cols (4 col-tiles of 32); wave holds 32 A-rows in
// regs (qf[16][2] = 128 VGPR). kt loop: 2 ds_read_b128 -> 4 MFMA, no barriers.
// grid (64, 4, nets) = 768 blocks for 3 nets -> 3 blocks/CU co-resident.
// ---------------------------------------------------------------------------
template<int ACT>
__global__ __launch_bounds__(256) void gemm_rs(
    const u16* __restrict__ Abase, const u16* __restrict__ Wt0, size_t wstride,
    P3 bias, u16* __restrict__ Cbase)
{
    __shared__ u16 Ws[32 * KSTR];   // 33,280 B

    const int net = blockIdx.z;
    const u16* A  = Abase + (size_t)net * NXR * HD;
    const u16* Wt = Wt0 + (size_t)net * wstride;
    const float* bias_p = bias.p[net];
    u16* C = Cbase + (size_t)net * NXR * HD;

    const int tid = threadIdx.x;
    const int wave = tid >> 6, lane = tid & 63;
    const int row0 = blockIdx.x * 128;
    const int colbase = blockIdx.y * 128;

    const int qm = lane & 15;
    const int g  = lane >> 4;

    // A fragments for this wave's 32 rows, all K: 32 x s16x8 = 128 VGPRs.
    s16x8 qf[16][2];
    {
        const u16* ap = A + (size_t)(row0 + wave * 32 + qm) * HD + g * 8;
#pragma unroll
        for (int t = 0; t < 16; ++t) {
            qf[t][0] = *(const s16x8*)(ap + t * 32);
            qf[t][1] = *(const s16x8*)(ap + (size_t)16 * HD + t * 32);
        }
    }

    for (int ct = 0; ct < 4; ++ct) {
        const int col0 = colbase + ct * 32;

        // stage W tile [32 cols][512] into LDS
#pragma unroll
        for (int i = 0; i < 8; ++i) {
            int chunk = i * 256 + tid;
            int cc = chunk >> 6;
            int ch = chunk & 63;
            s16x8 v = *(const s16x8*)(Wt + (size_t)(col0 + cc) * HD + ch * 8);
            *(s16x8*)&Ws[cc * KSTR + ch * 8] = v;
        }
        __syncthreads();

        f32x4 acc[2][2] = {};
#pragma unroll
        for (int kt = 0; kt < 16; ++kt) {
            s16x8 b0 = *(const s16x8*)&Ws[qm * KSTR + kt * 32 + g * 8];
            s16x8 b1 = *(const s16x8*)&Ws[(16 + qm) * KSTR + kt * 32 + g * 8];
            acc[0][0] = __builtin_amdgcn_mfma_f32_16x16x32_bf16(qf[kt][0], b0, acc[0][0], 0, 0, 0);
            acc[0][1] = __builtin_amdgcn_mfma_f32_16x16x32_bf16(qf[kt][0], b1, acc[0][1], 0, 0, 0);
            acc[1][0] = __builtin_amdgcn_mfma_f32_16x16x32_bf16(qf[kt][1], b0, acc[1][0], 0, 0, 0);
            acc[1][1] = __builtin_amdgcn_mfma_f32_16x16x32_bf16(qf[kt][1], b1, acc[1][1], 0, 0, 0);
        }

        // epilogue: bias + act + bf16 store (C/D: col=lane&15, row=g*4+r)
        float bv0 = bias_p[col0 + qm];
        float bv1 = bias_p[col0 + 16 + qm];
#pragma unroll
        for (int h = 0; h < 2; ++h) {
#pragma unroll
            for (int r = 0; r < 4; ++r) {
                int grow = row0 + wave * 32 + h * 16 + g * 4 + r;
                float v0 = acc[h][0][r] + bv0;
                float v1 = acc[h][1][r] + bv1;
                if (ACT) { v0 = __sinf(v0); v1 = __sinf(v1); }
                C[(size_t)grow * HD + col0 + qm]      = f2bf(v0);
                C[(size_t)grow * HD + col0 + 16 + qm] = f2bf(v1);
            }
        }
        __syncthreads();
    }
}

// ---------------------------------------------------------------------------
// V output layer (M=3), one wave per row, fp32 out.
// ---------------------------------------------------------------------------
__global__ __launch_bounds__(256) void vout_k(
    const u16* __restrict__ H, const float* __restrict__ Wo,
    const float* __restrict__ bo, float* __restrict__ V)
{
    int wave = threadIdx.x >> 6, lane = threadIdx.x & 63;
    int row = blockIdx.x * 4 + wave;
    s16x8 hv = *(const s16x8*)(H + (size_t)row * HD + lane * 8);
    float a0 = 0, a1 = 0, a2 = 0;
#pragma unroll
    for (int j = 0; j < 8; ++j) {
        float hf = bf2f(((const u16*)&hv)[j]);
        int k = lane * 8 + j;
        a0 += hf * Wo[k * 3 + 0];
        a1 += hf * Wo[k * 3 + 1];
        a2 += hf * Wo[k * 3 + 2];
    }
#pragma unroll
    for (int d = 32; d >= 1; d >>= 1) {
        a0 += __shfl_down(a0, d);
        a1 += __shfl_down(a1, d);
        a2 += __shfl_down(a2, d);
    }
    if (lane == 0) {
        V[row * 3 + 0] = a0 + bo[0];
        V[row * 3 + 1] = a1 + bo[1];
        V[row * 3 + 2] = a2 + bo[2];
    }
}

// ---------------------------------------------------------------------------
// Fused attention v5: Q-in-registers (32 rows/wave), K-in-LDS.
// Block = 128 Q-rows x JC=512 cols; grid (NSL=16, 64) = 1024 blocks
// -> 4 blocks/CU co-resident (VGPR 120 -> 4 waves/SIMD; LDS 33.3KBx4 <= 160).
// kt loop: 2 ds_read_b128 feed 4 MFMAs, no barriers inside.
// ---------------------------------------------------------------------------
__global__ __launch_bounds__(256) void attn_mfma(
    const u16* __restrict__ Q, const u16* __restrict__ K,
    const float* __restrict__ V, float* __restrict__ out)
{
    __shared__ u16 Ks[32 * KSTR];   // 33,280 B

    const int tid = threadIdx.x;
    const int wave = tid >> 6, lane = tid & 63;
    const int row0 = blockIdx.y * 128;
    const int col_base = blockIdx.x * JC;

    const int qm = lane & 15;
    const int g  = lane >> 4;

    // Q fragments: 32 rows x all K = 32 x s16x8 = 128 VGPRs, loaded once.
    s16x8 qf[16][2];
    {
        const u16* qp = Q + (size_t)(row0 + wave * 32 + qm) * HD + g * 8;
#pragma unroll
        for (int t = 0; t < 16; ++t) {
            qf[t][0] = *(const s16x8*)(qp + t * 32);
            qf[t][1] = *(const s16x8*)(qp + (size_t)16 * HD + t * 32);
        }
    }

    float po[2][4][3] = {};   // [rowfrag][r][c], accumulated over all j

    for (int jt = 0; jt < JC / 32; ++jt) {
        const int col0 = col_base + jt * 32;

        // stage K tile [32 cols][512] into LDS
#pragma unroll
        for (int i = 0; i < 8; ++i) {
            int chunk = i * 256 + tid;
            int cc = chunk >> 6;
            int ch = chunk & 63;
            s16x8 v = *(const s16x8*)(K + (size_t)(col0 + cc) * HD + ch * 8);
            *(s16x8*)&Ks[cc * KSTR + ch * 8] = v;
        }
        __syncthreads();

        // V rows for this tile
        float vv[2][3];
#pragma unroll
        for (int ct = 0; ct < 2; ++ct) {
            size_t vr = (size_t)(col0 + ct * 16 + qm) * 3;
            vv[ct][0] = V[vr + 0];
            vv[ct][1] = V[vr + 1];
            vv[ct][2] = V[vr + 2];
        }

        f32x4 acc[2][2] = {};
#pragma unroll
        for (int kt = 0; kt < 16; ++kt) {
            s16x8 b0 = *(const s16x8*)&Ks[qm * KSTR + kt * 32 + g * 8];
            s16x8 b1 = *(const s16x8*)&Ks[(16 + qm) * KSTR + kt * 32 + g * 8];
            acc[0][0] = __builtin_amdgcn_mfma_f32_16x16x32_bf16(qf[kt][0], b0, acc[0][0], 0, 0, 0);
            acc[0][1] = __builtin_amdgcn_mfma_f32_16x16x32_bf16(qf[kt][0], b1, acc[0][1], 0, 0, 0);
            acc[1][0] = __builtin_amdgcn_mfma_f32_16x16x32_bf16(qf[kt][1], b0, acc[1][0], 0, 0, 0);
            acc[1][1] = __builtin_amdgcn_mfma_f32_16x16x32_bf16(qf[kt][1], b1, acc[1][1], 0, 0, 0);
        }

        // sigmoid + PV (rcp = v_rcp_f32, 1 ulp)
#pragma unroll
        for (int h = 0; h < 2; ++h)
#pragma unroll
            for (int ct = 0; ct < 2; ++ct)
#pragma unroll
                for (int r = 0; r < 4; ++r) {
                    float s = __builtin_amdgcn_rcpf(1.f + __expf(-acc[h][ct][r]));
                    po[h][r][0] += s * vv[ct][0];
                    po[h][r][1] += s * vv[ct][1];
                    po[h][r][2] += s * vv[ct][2];
                }
        __syncthreads();   // Ks reused next tile
    }

    // reduce over the 16 col-lanes; rows are wave-private
#pragma unroll
    for (int h = 0; h < 2; ++h)
#pragma unroll
        for (int r = 0; r < 4; ++r)
#pragma unroll
            for (int c = 0; c < 3; ++c) {
                float v = po[h][r][c];
                v += __shfl_down(v, 8, 16);
                v += __shfl_down(v, 4, 16);
                v += __shfl_down(v, 2, 16);
                v += __shfl_down(v, 1, 16);
                if (qm == 0)
                    atomicAdd(&out[(size_t)(row0 + wave * 32 + h * 16 + g * 4 + r) * 3 + c], v);
            }
}

// ---------------------------------------------------------------------------
// Workspace layouts:
//  FUSED (needs >=57 MB):  [0,6) wT | [6,30) hA (3 nets) | [30,54) hB | [54,..) Vf
//  FALLBACK (38.1 MB):     [0,6) wT | [6,22) R1 (2 nets) | [22,38) R2 | [38,..) Vf
// ---------------------------------------------------------------------------
extern "C" void kernel_launch(void* const* d_in, const int* in_sizes, int n_in,
                              void* d_out, int out_size, void* d_ws, size_t ws_size,
                              hipStream_t stream)
{
    const float* x   = (const float*)d_in[0];
    const float* c   = (const float*)d_in[1];
    const float* QW0 = (const float*)d_in[2];
    const float* Qb0 = (const float*)d_in[3];
    const float* QWh = (const float*)d_in[4];
    const float* Qbh = (const float*)d_in[5];
    const float* QWo = (const float*)d_in[6];
    const float* Qbo = (const float*)d_in[7];
    const float* KW0 = (const float*)d_in[8];
    const float* Kb0 = (const float*)d_in[9];
    const float* KWh = (const float*)d_in[10];
    const float* Kbh = (const float*)d_in[11];
    const float* KWo = (const float*)d_in[12];
    const float* Kbo = (const float*)d_in[13];
    const float* VW0 = (const float*)d_in[14];
    const float* Vb0 = (const float*)d_in[15];
    const float* VWh = (const float*)d_in[16];
    const float* Vbh = (const float*)d_in[17];
    const float* VWo = (const float*)d_in[18];
    const float* Vbo = (const float*)d_in[19];

    char* ws = (char*)d_ws;
    const size_t WTN = (size_t)HD * HD;
    const size_t MB = 1048576;
    const size_t NET = (size_t)NXR * HD;

    // ---- weight transposes (1 dispatch, both paths) ----
    u16* wT = (u16*)ws;
    P11 tsrc;
    for (int l = 0; l < 3; ++l) {
        tsrc.p[l * 3 + 0] = QWh + (size_t)l * WTN;
        tsrc.p[l * 3 + 1] = KWh + (size_t)l * WTN;
        tsrc.p[l * 3 + 2] = VWh + (size_t)l * WTN;
    }
    tsrc.p[9]  = QWo;
    tsrc.p[10] = KWo;
    transpose_w_all<<<dim3(16, 16, 11), 256, 0, stream>>>(tsrc, wT);

    const int L0G = NXR * HD / 2048;  // 2048
    const u16* Qb; const u16* Kb; const float* Vf;

    if (ws_size >= 57 * MB) {
        // ================= fused path =================
        u16*   hA = (u16*)(ws + 6 * MB);
        u16*   hB = (u16*)(ws + 30 * MB);
        float* Vff = (float*)(ws + 54 * MB);

        P3 w0 = {{QW0, KW0, VW0}}, b0 = {{Qb0, Kb0, Vb0}};
        layer0_all<<<dim3(L0G, 1, 3), 256, 0, stream>>>(x, c, w0, b0, hA, 0);

        dim3 g3(NXR / 128, HD / 128, 3);
        {
            P3 b = {{Qbh + 0 * HD, Kbh + 0 * HD, Vbh + 0 * HD}};
            gemm_rs<1><<<g3, 256, 0, stream>>>(hA, wT + 0 * 3 * WTN, WTN, b, hB);
        }
        {
            P3 b = {{Qbh + 1 * HD, Kbh + 1 * HD, Vbh + 1 * HD}};
            gemm_rs<1><<<g3, 256, 0, stream>>>(hB, wT + 1 * 3 * WTN, WTN, b, hA);
        }
        {
            P3 b = {{Qbh + 2 * HD, Kbh + 2 * HD, Vbh + 2 * HD}};
            gemm_rs<1><<<g3, 256, 0, stream>>>(hA, wT + 2 * 3 * WTN, WTN, b, hB);
        }
        {
            P3 b = {{Qbo, Kbo, nullptr}};
            gemm_rs<0><<<dim3(NXR / 128, HD / 128, 2), 256, 0, stream>>>(
                hB, wT + 9 * WTN, WTN, b, hA);
        }
        vout_k<<<NCR / 4, 256, 0, stream>>>(hB + 2 * NET, VWo, Vbo, Vff);

        Qb = hA; Kb = hA + NET; Vf = Vff;
    } else {
        // ================= two-phase fallback (proven 38.1 MB) =================
        u16*   R1 = (u16*)(ws + 6 * MB);
        u16*   R2 = (u16*)(ws + 22 * MB);
        float* Vff = (float*)(ws + 38 * MB);

        {
            P3 w0 = {{VW0, nullptr, nullptr}}, b0 = {{Vb0, nullptr, nullptr}};
            layer0_all<<<dim3(L0G, 1, 1), 256, 0, stream>>>(x, c, w0, b0, R1, 2);
        }
        dim3 gv(NXR / 128, HD / 128, 1);
        {
            P3 b = {{Vbh + 0 * HD, nullptr, nullptr}};
            gemm_rs<1><<<gv, 256, 0, stream>>>(R1, wT + (0 * 3 + 2) * WTN, 0, b, R2);
        }
        {
            P3 b = {{Vbh + 1 * HD, nullptr, nullptr}};
            gemm_rs<1><<<gv, 256, 0, stream>>>(R2, wT + (1 * 3 + 2) * WTN, 0, b, R1);
        }
        {
            P3 b = {{Vbh + 2 * HD, nullptr, nullptr}};
            gemm_rs<1><<<gv, 256, 0, stream>>>(R1, wT + (2 * 3 + 2) * WTN, 0, b, R2);
        }
        vout_k<<<NCR / 4, 256, 0, stream>>>(R2, VWo, Vbo, Vff);

        {
            P3 w0 = {{QW0, KW0, nullptr}}, b0 = {{Qb0, Kb0, nullptr}};
            layer0_all<<<dim3(L0G, 1, 2), 256, 0, stream>>>(x, c, w0, b0, R1, 0);
        }
        dim3 gqk(NXR / 128, HD / 128, 2);
        {
            P3 b = {{Qbh + 0 * HD, Kbh + 0 * HD, nullptr}};
            gemm_rs<1><<<gqk, 256, 0, stream>>>(R1, wT + 0 * 3 * WTN, WTN, b, R2);
        }
        {
            P3 b = {{Qbh + 1 * HD, Kbh + 1 * HD, nullptr}};
            gemm_rs<1><<<gqk, 256, 0, stream>>>(R2, wT + 1 * 3 * WTN, WTN, b, R1);
        }
        {
            P3 b = {{Qbh + 2 * HD, Kbh + 2 * HD, nullptr}};
            gemm_rs<1><<<gqk, 256, 0, stream>>>(R1, wT + 2 * 3 * WTN, WTN, b, R2);
        }
        {
            P3 b = {{Qbo, Kbo, nullptr}};
            gemm_rs<0><<<gqk, 256, 0, stream>>>(R2, wT + 9 * WTN, WTN, b, R1);
        }
        Qb = R1; Kb = R1 + NET; Vf = Vff;
    }

    // ---- attention ----
    hipMemsetAsync(d_out, 0, (size_t)out_size * sizeof(float), stream);
    attn_mfma<<<dim3(NSL, NXR / 128), 256, 0, stream>>>(Qb, Kb, Vf, (float*)d_out);
}

// Round 13
// 293.327 us; speedup vs baseline: 1.9111x; 1.0443x over previous
//
#include <hip/hip_runtime.h>
#include <math.h>

#define NXR 8192
#define NCR 8192
#define HD  512
#define NSL 8            // attention j-slices (proven best R11)
#define JC  (NCR / NSL)  // 1024 cols per attention block
#define KSTR 520         // padded LDS col stride (elems)

typedef short s16x8 __attribute__((ext_vector_type(8)));
typedef float f32x4 __attribute__((ext_vector_type(4)));
typedef unsigned short u16;

struct P11 { const float* p[11]; };
struct P3  { const float* p[3]; };

__device__ inline u16 f2bf(float f) {
    unsigned int u = __float_as_uint(f);
    u = (u + 0x7FFFu + ((u >> 16) & 1u)) >> 16;
    return (u16)u;
}
__device__ inline float bf2f(u16 h) {
    return __uint_as_float(((unsigned int)h) << 16);
}

// ---------------------------------------------------------------------------
// Fused weight transpose + bf16 convert: out[z][n][k] = (bf16)in_z[k][n].
// ---------------------------------------------------------------------------
__global__ __launch_bounds__(256) void transpose_w_all(
    P11 srcs, u16* __restrict__ out)
{
    const float* in = srcs.p[blockIdx.z];
    u16* o = out + (size_t)blockIdx.z * HD * HD;
    __shared__ float tile[32][33];
    int bx = blockIdx.x * 32, by = blockIdx.y * 32;
    int tx = threadIdx.x & 31, ty = threadIdx.x >> 5;
    for (int r = ty; r < 32; r += 8)
        tile[r][tx] = in[(size_t)(by + r) * HD + bx + tx];
    __syncthreads();
    for (int r = ty; r < 32; r += 8)
        o[(size_t)(bx + r) * HD + by + tx] = f2bf(tile[tx][r]);
}

// ---------------------------------------------------------------------------
// Layer 0, 8 outputs/thread, bf16x8 store. grid (NXR*HD/2048, 1, nz)
// ---------------------------------------------------------------------------
__global__ __launch_bounds__(256) void layer0_all(
    const float* __restrict__ x, const float* __restrict__ c,
    P3 W0p, P3 b0p, u16* __restrict__ H, int net_base)
{
    int z = blockIdx.z;
    int net = net_base + z;
    const float* X  = (net == 0) ? x : c;
    const float* W0 = W0p.p[z];
    const float* b0 = b0p.p[z];
    u16* Hn = H + (size_t)z * NXR * HD;

    int idx = (blockIdx.x * 256 + threadIdx.x) * 8;
    int n = idx & (HD - 1);
    int row = idx >> 9;
    float x0 = X[row * 3 + 0], x1 = X[row * 3 + 1], x2 = X[row * 3 + 2];
    s16x8 o;
#pragma unroll
    for (int j = 0; j < 8; ++j) {
        float v = x0 * W0[n + j] + x1 * W0[HD + n + j] + x2 * W0[2 * HD + n + j] + b0[n + j];
        ((u16*)&o)[j] = f2bf(__sinf(v));
    }
    *(s16x8*)&Hn[idx] = o;
}

// ---------------------------------------------------------------------------
// GEMM v4 (A-in-registers, W-in-LDS, REGISTER-PREFETCH pipeline):
// per tile: barrier; ds_write(pre); barrier; prefetch(next)->pre; MFMAs.
// Global latency of tile jt+1 hides behind tile jt's MFMA loop.
// Block = 128 rows x 128 cols (4 col-tiles); grid (64, 4, nets).
// ---------------------------------------------------------------------------
template<int ACT>
__global__ __launch_bounds__(256) void gemm_rs(
    const u16* __restrict__ Abase, const u16* __restrict__ Wt0, size_t wstride,
    P3 bias, u16* __restrict__ Cbase)
{
    __shared__ u16 Ws[32 * KSTR];   // 33,280 B

    const int net = blockIdx.z;
    const u16* A  = Abase + (size_t)net * NXR * HD;
    const u16* Wt = Wt0 + (size_t)net * wstride;
    const float* bias_p = bias.p[net];
    u16* C = Cbase + (size_t)net * NXR * HD;

    const int tid = threadIdx.x;
    const int wave = tid >> 6, lane = tid & 63;
    const int row0 = blockIdx.x * 128;
    const int colbase = blockIdx.y * 128;

    const int qm = lane & 15;
    const int g  = lane >> 4;

    // prefetch col-tile 0 into registers
    s16x8 pre[8];
#pragma unroll
    for (int i = 0; i < 8; ++i) {
        int chunk = i * 256 + tid;
        pre[i] = *(const s16x8*)(Wt + (size_t)(colbase + (chunk >> 6)) * HD + (chunk & 63) * 8);
    }

    // A fragments for this wave's 32 rows, all K (parked in AGPRs by compiler)
    s16x8 qf[16][2];
    {
        const u16* ap = A + (size_t)(row0 + wave * 32 + qm) * HD + g * 8;
#pragma unroll
        for (int t = 0; t < 16; ++t) {
            qf[t][0] = *(const s16x8*)(ap + t * 32);
            qf[t][1] = *(const s16x8*)(ap + (size_t)16 * HD + t * 32);
        }
    }

    for (int ct = 0; ct < 4; ++ct) {
        const int col0 = colbase + ct * 32;

        __syncthreads();   // previous tile's reads complete
#pragma unroll
        for (int i = 0; i < 8; ++i) {
            int chunk = i * 256 + tid;
            *(s16x8*)&Ws[(chunk >> 6) * KSTR + (chunk & 63) * 8] = pre[i];
        }
        __syncthreads();

        if (ct + 1 < 4) {
            const int ncol = colbase + (ct + 1) * 32;
#pragma unroll
            for (int i = 0; i < 8; ++i) {
                int chunk = i * 256 + tid;
                pre[i] = *(const s16x8*)(Wt + (size_t)(ncol + (chunk >> 6)) * HD + (chunk & 63) * 8);
            }
        }

        f32x4 acc[2][2] = {};
#pragma unroll
        for (int kt = 0; kt < 16; ++kt) {
            s16x8 b0 = *(const s16x8*)&Ws[qm * KSTR + kt * 32 + g * 8];
            s16x8 b1 = *(const s16x8*)&Ws[(16 + qm) * KSTR + kt * 32 + g * 8];
            acc[0][0] = __builtin_amdgcn_mfma_f32_16x16x32_bf16(qf[kt][0], b0, acc[0][0], 0, 0, 0);
            acc[0][1] = __builtin_amdgcn_mfma_f32_16x16x32_bf16(qf[kt][0], b1, acc[0][1], 0, 0, 0);
            acc[1][0] = __builtin_amdgcn_mfma_f32_16x16x32_bf16(qf[kt][1], b0, acc[1][0], 0, 0, 0);
            acc[1][1] = __builtin_amdgcn_mfma_f32_16x16x32_bf16(qf[kt][1], b1, acc[1][1], 0, 0, 0);
        }

        // epilogue: bias + act + bf16 store (C/D: col=lane&15, row=g*4+r)
        float bv0 = bias_p[col0 + qm];
        float bv1 = bias_p[col0 + 16 + qm];
#pragma unroll
        for (int h = 0; h < 2; ++h) {
#pragma unroll
            for (int r = 0; r < 4; ++r) {
                int grow = row0 + wave * 32 + h * 16 + g * 4 + r;
                float v0 = acc[h][0][r] + bv0;
                float v1 = acc[h][1][r] + bv1;
                if (ACT) { v0 = __sinf(v0); v1 = __sinf(v1); }
                C[(size_t)grow * HD + col0 + qm]      = f2bf(v0);
                C[(size_t)grow * HD + col0 + 16 + qm] = f2bf(v1);
            }
        }
    }
}

// ---------------------------------------------------------------------------
// V output layer (M=3), one wave per row, fp32 out.
// ---------------------------------------------------------------------------
__global__ __launch_bounds__(256) void vout_k(
    const u16* __restrict__ H, const float* __restrict__ Wo,
    const float* __restrict__ bo, float* __restrict__ V)
{
    int wave = threadIdx.x >> 6, lane = threadIdx.x & 63;
    int row = blockIdx.x * 4 + wave;
    s16x8 hv = *(const s16x8*)(H + (size_t)row * HD + lane * 8);
    float a0 = 0, a1 = 0, a2 = 0;
#pragma unroll
    for (int j = 0; j < 8; ++j) {
        float hf = bf2f(((const u16*)&hv)[j]);
        int k = lane * 8 + j;
        a0 += hf * Wo[k * 3 + 0];
        a1 += hf * Wo[k * 3 + 1];
        a2 += hf * Wo[k * 3 + 2];
    }
#pragma unroll
    for (int d = 32; d >= 1; d >>= 1) {
        a0 += __shfl_down(a0, d);
        a1 += __shfl_down(a1, d);
        a2 += __shfl_down(a2, d);
    }
    if (lane == 0) {
        V[row * 3 + 0] = a0 + bo[0];
        V[row * 3 + 1] = a1 + bo[1];
        V[row * 3 + 2] = a2 + bo[2];
    }
}

// ---------------------------------------------------------------------------
// Fused attention v6: Q-in-registers (32 rows/wave), K-in-LDS with
// REGISTER-PREFETCH pipeline. Block = 128 rows x JC=1024 cols (32 tiles);
// grid (NSL=8, 64) = 512 blocks.
// ---------------------------------------------------------------------------
__global__ __launch_bounds__(256) void attn_mfma(
    const u16* __restrict__ Q, const u16* __restrict__ K,
    const float* __restrict__ V, float* __restrict__ out)
{
    __shared__ u16 Ks[32 * KSTR];   // 33,280 B

    const int tid = threadIdx.x;
    const int wave = tid >> 6, lane = tid & 63;
    const int row0 = blockIdx.y * 128;
    const int col_base = blockIdx.x * JC;

    const int qm = lane & 15;
    const int g  = lane >> 4;

    // prefetch K tile 0 into registers
    s16x8 pre[8];
#pragma unroll
    for (int i = 0; i < 8; ++i) {
        int chunk = i * 256 + tid;
        pre[i] = *(const s16x8*)(K + (size_t)(col_base + (chunk >> 6)) * HD + (chunk & 63) * 8);
    }

    // Q fragments: 32 rows x all K (parked in AGPRs by compiler)
    s16x8 qf[16][2];
    {
        const u16* qp = Q + (size_t)(row0 + wave * 32 + qm) * HD + g * 8;
#pragma unroll
        for (int t = 0; t < 16; ++t) {
            qf[t][0] = *(const s16x8*)(qp + t * 32);
            qf[t][1] = *(const s16x8*)(qp + (size_t)16 * HD + t * 32);
        }
    }

    float po[2][4][3] = {};   // [rowfrag][r][c], accumulated over all j

    for (int jt = 0; jt < JC / 32; ++jt) {
        const int col0 = col_base + jt * 32;

        __syncthreads();   // previous tile's reads complete
#pragma unroll
        for (int i = 0; i < 8; ++i) {
            int chunk = i * 256 + tid;
            *(s16x8*)&Ks[(chunk >> 6) * KSTR + (chunk & 63) * 8] = pre[i];
        }
        __syncthreads();

        if (jt + 1 < JC / 32) {
            const int ncol = col_base + (jt + 1) * 32;
#pragma unroll
            for (int i = 0; i < 8; ++i) {
                int chunk = i * 256 + tid;
                pre[i] = *(const s16x8*)(K + (size_t)(ncol + (chunk >> 6)) * HD + (chunk & 63) * 8);
            }
        }

        // V rows for this tile
        float vv[2][3];
#pragma unroll
        for (int ct = 0; ct < 2; ++ct) {
            size_t vr = (size_t)(col0 + ct * 16 + qm) * 3;
            vv[ct][0] = V[vr + 0];
            vv[ct][1] = V[vr + 1];
            vv[ct][2] = V[vr + 2];
        }

        f32x4 acc[2][2] = {};
#pragma unroll
        for (int kt = 0; kt < 16; ++kt) {
            s16x8 b0 = *(const s16x8*)&Ks[qm * KSTR + kt * 32 + g * 8];
            s16x8 b1 = *(const s16x8*)&Ks[(16 + qm) * KSTR + kt * 32 + g * 8];
            acc[0][0] = __builtin_amdgcn_mfma_f32_16x16x32_bf16(qf[kt][0], b0, acc[0][0], 0, 0, 0);
            acc[0][1] = __builtin_amdgcn_mfma_f32_16x16x32_bf16(qf[kt][0], b1, acc[0][1], 0, 0, 0);
            acc[1][0] = __builtin_amdgcn_mfma_f32_16x16x32_bf16(qf[kt][1], b0, acc[1][0], 0, 0, 0);
            acc[1][1] = __builtin_amdgcn_mfma_f32_16x16x32_bf16(qf[kt][1], b1, acc[1][1], 0, 0, 0);
        }

        // sigmoid + PV (rcp = v_rcp_f32, 1 ulp)
#pragma unroll
        for (int h = 0; h < 2; ++h)
#pragma unroll
            for (int ct = 0; ct < 2; ++ct)
#pragma unroll
                for (int r = 0; r < 4; ++r) {
                    float s = __builtin_amdgcn_rcpf(1.f + __expf(-acc[h][ct][r]));
                    po[h][r][0] += s * vv[ct][0];
                    po[h][r][1] += s * vv[ct][1];
                    po[h][r][2] += s * vv[ct][2];
                }
    }

    // reduce over the 16 col-lanes; rows are wave-private
#pragma unroll
    for (int h = 0; h < 2; ++h)
#pragma unroll
        for (int r = 0; r < 4; ++r)
#pragma unroll
            for (int c = 0; c < 3; ++c) {
                float v = po[h][r][c];
                v += __shfl_down(v, 8, 16);
                v += __shfl_down(v, 4, 16);
                v += __shfl_down(v, 2, 16);
                v += __shfl_down(v, 1, 16);
                if (qm == 0)
                    atomicAdd(&out[(size_t)(row0 + wave * 32 + h * 16 + g * 4 + r) * 3 + c], v);
            }
}

// ---------------------------------------------------------------------------
// Workspace layouts:
//  FUSED (needs >=57 MB):  [0,6) wT | [6,30) hA (3 nets) | [30,54) hB | [54,..) Vf
//  FALLBACK (38.1 MB):     [0,6) wT | [6,22) R1 (2 nets) | [22,38) R2 | [38,..) Vf
// ---------------------------------------------------------------------------
extern "C" void kernel_launch(void* const* d_in, const int* in_sizes, int n_in,
                              void* d_out, int out_size, void* d_ws, size_t ws_size,
                              hipStream_t stream)
{
    const float* x   = (const float*)d_in[0];
    const float* c   = (const float*)d_in[1];
    const float* QW0 = (const float*)d_in[2];
    const float* Qb0 = (const float*)d_in[3];
    const float* QWh = (const float*)d_in[4];
    const float* Qbh = (const float*)d_in[5];
    const float* QWo = (const float*)d_in[6];
    const float* Qbo = (const float*)d_in[7];
    const float* KW0 = (const float*)d_in[8];
    const float* Kb0 = (const float*)d_in[9];
    const float* KWh = (const float*)d_in[10];
    const float* Kbh = (const float*)d_in[11];
    const float* KWo = (const float*)d_in[12];
    const float* Kbo = (const float*)d_in[13];
    const float* VW0 = (const float*)d_in[14];
    const float* Vb0 = (const float*)d_in[15];
    const float* VWh = (const float*)d_in[16];
    const float* Vbh = (const float*)d_in[17];
    const float* VWo = (const float*)d_in[18];
    const float* Vbo = (const float*)d_in[19];

    char* ws = (char*)d_ws;
    const size_t WTN = (size_t)HD * HD;
    const size_t MB = 1048576;
    const size_t NET = (size_t)NXR * HD;

    // ---- weight transposes (1 dispatch, both paths) ----
    u16* wT = (u16*)ws;
    P11 tsrc;
    for (int l = 0; l < 3; ++l) {
        tsrc.p[l * 3 + 0] = QWh + (size_t)l * WTN;
        tsrc.p[l * 3 + 1] = KWh + (size_t)l * WTN;
        tsrc.p[l * 3 + 2] = VWh + (size_t)l * WTN;
    }
    tsrc.p[9]  = QWo;
    tsrc.p[10] = KWo;
    transpose_w_all<<<dim3(16, 16, 11), 256, 0, stream>>>(tsrc, wT);

    const int L0G = NXR * HD / 2048;  // 2048
    const u16* Qb; const u16* Kb; const float* Vf;

    if (ws_size >= 57 * MB) {
        // ================= fused path =================
        u16*   hA = (u16*)(ws + 6 * MB);
        u16*   hB = (u16*)(ws + 30 * MB);
        float* Vff = (float*)(ws + 54 * MB);

        P3 w0 = {{QW0, KW0, VW0}}, b0 = {{Qb0, Kb0, Vb0}};
        layer0_all<<<dim3(L0G, 1, 3), 256, 0, stream>>>(x, c, w0, b0, hA, 0);

        dim3 g3(NXR / 128, HD / 128, 3);
        {
            P3 b = {{Qbh + 0 * HD, Kbh + 0 * HD, Vbh + 0 * HD}};
            gemm_rs<1><<<g3, 256, 0, stream>>>(hA, wT + 0 * 3 * WTN, WTN, b, hB);
        }
        {
            P3 b = {{Qbh + 1 * HD, Kbh + 1 * HD, Vbh + 1 * HD}};
            gemm_rs<1><<<g3, 256, 0, stream>>>(hB, wT + 1 * 3 * WTN, WTN, b, hA);
        }
        {
            P3 b = {{Qbh + 2 * HD, Kbh + 2 * HD, Vbh + 2 * HD}};
            gemm_rs<1><<<g3, 256, 0, stream>>>(hA, wT + 2 * 3 * WTN, WTN, b, hB);
        }
        {
            P3 b = {{Qbo, Kbo, nullptr}};
            gemm_rs<0><<<dim3(NXR / 128, HD / 128, 2), 256, 0, stream>>>(
                hB, wT + 9 * WTN, WTN, b, hA);
        }
        vout_k<<<NCR / 4, 256, 0, stream>>>(hB + 2 * NET, VWo, Vbo, Vff);

        Qb = hA; Kb = hA + NET; Vf = Vff;
    } else {
        // ================= two-phase fallback (proven 38.1 MB) =================
        u16*   R1 = (u16*)(ws + 6 * MB);
        u16*   R2 = (u16*)(ws + 22 * MB);
        float* Vff = (float*)(ws + 38 * MB);

        {
            P3 w0 = {{VW0, nullptr, nullptr}}, b0 = {{Vb0, nullptr, nullptr}};
            layer0_all<<<dim3(L0G, 1, 1), 256, 0, stream>>>(x, c, w0, b0, R1, 2);
        }
        dim3 gv(NXR / 128, HD / 128, 1);
        {
            P3 b = {{Vbh + 0 * HD, nullptr, nullptr}};
            gemm_rs<1><<<gv, 256, 0, stream>>>(R1, wT + (0 * 3 + 2) * WTN, 0, b, R2);
        }
        {
            P3 b = {{Vbh + 1 * HD, nullptr, nullptr}};
            gemm_rs<1><<<gv, 256, 0, stream>>>(R2, wT + (1 * 3 + 2) * WTN, 0, b, R1);
        }
        {
            P3 b = {{Vbh + 2 * HD, nullptr, nullptr}};
            gemm_rs<1><<<gv, 256, 0, stream>>>(R1, wT + (2 * 3 + 2) * WTN, 0, b, R2);
        }
        vout_k<<<NCR / 4, 256, 0, stream>>>(R2, VWo, Vbo, Vff);

        {
            P3 w0 = {{QW0, KW0, nullptr}}, b0 = {{Qb0, Kb0, nullptr}};
            layer0_all<<<dim3(L0G, 1, 2), 256, 0, stream>>>(x, c, w0, b0, R1, 0);
        }
        dim3 gqk(NXR / 128, HD / 128, 2);
        {
            P3 b = {{Qbh + 0 * HD, Kbh + 0 * HD, nullptr}};
            gemm_rs<1><<<gqk, 256, 0, stream>>>(R1, wT + 0 * 3 * WTN, WTN, b, R2);
        }
        {
            P3 b = {{Qbh + 1 * HD, Kbh + 1 * HD, nullptr}};
            gemm_rs<1><<<gqk, 256, 0, stream>>>(R2, wT + 1 * 3 * WTN, WTN, b, R1);
        }
        {
            P3 b = {{Qbh + 2 * HD, Kbh + 2 * HD, nullptr}};
            gemm_rs<1><<<gqk, 256, 0, stream>>>(R1, wT + 2 * 3 * WTN, WTN, b, R2);
        }
        {
            P3 b = {{Qbo, Kbo, nullptr}};
            gemm_rs<0><<<gqk, 256, 0, stream>>>(R2, wT + 9 * WTN, WTN, b, R1);
        }
        Qb = R1; Kb = R1 + NET; Vf = Vff;
    }

    // ---- attention ----
    hipMemsetAsync(d_out, 0, (size_t)out_size * sizeof(float), stream);
    attn_mfma<<<dim3(NSL, NXR / 128), 256, 0, stream>>>(Qb, Kb, Vf, (float*)d_out);
}